// Round 9
// baseline (973.441 us; speedup 1.0000x reference)
//
#include <hip/hip_runtime.h>
#include <hip/hip_bf16.h>
#include <cstdint>
#include <cstddef>

typedef __hip_bfloat16 bf16;
typedef unsigned short ushort;
typedef __attribute__((ext_vector_type(8))) short bf16x8;
typedef __attribute__((ext_vector_type(4))) float f32x4;

#define HDIM 256
#define NVOCAB 26
#define STR 264

// ---- workspace layout (float offsets) ----
#define OFF_BSUM  16
#define OFF_Z1    (OFF_BSUM+1024)
#define OFF_HH1   (OFF_Z1+1024)
#define OFF_H1    (OFF_HH1+1024)
#define OFF_C1    (OFF_H1+256)
#define OFF_WCH1  (OFF_C1+256)
#define OFF_BTF   (OFF_WCH1+256)
#define OFF_EWC   (OFF_BTF+256)          // [26][256] f32
#define OFF_P8    (OFF_EWC+6656)         // [26][1024] f32
#define OFF_SCB   (OFF_P8+26624)         // [32][256] ushort (scomb bf16)
#define OFF_O8B   (OFF_SCB+4096)         // [32][256] ushort (out8 bf16)
#define OFF_H2B   (OFF_O8B+4096)         // [32][256] ushort (h2 per child0-id)
#define OFF_C2T   (OFF_H2B+4096)         // [32][256] f32
#define OFF_HH2A  (OFF_C2T+8192)         // [32][1024] f32 (bsum + W_hh@h2)
#define OFF_H3B   (OFF_HH2A+32768)       // [704][256] ushort (h3 per (id0,id1))
#define OFF_C3T   (OFF_H3B+90112)        // [704][256] f32
#define OFF_HH3   (OFF_C3T+180224)       // [704][1024] f32 (bsum + W_hh@h3)
#define OFF_FRAG  (OFF_HH3+720896)       // ushort frag tables
#define OFF_SLABS (OFF_FRAG+327680)

__device__ __forceinline__ float sigmf(float x){ return 1.0f/(1.0f+__expf(-x)); }
__device__ __forceinline__ float tanhfast(float x){ return 1.0f - 2.0f/(__expf(2.0f*x)+1.0f); }
__device__ __forceinline__ ushort f2b(float x){ bf16 h = __float2bfloat16(x); return *(ushort*)&h; }
__device__ __forceinline__ float ldin(const void* p, int i, int f32){
  if (f32) return ((const float*)p)[i];
  unsigned int w = ((unsigned int)((const ushort*)p)[i]) << 16;
  return __uint_as_float(w);
}
__device__ __forceinline__ void ld8(const void* p, int i, int f32, float* o){
  if (f32){
    float4 a = *(const float4*)((const float*)p + i);
    float4 b = *(const float4*)((const float*)p + i + 4);
    o[0]=a.x;o[1]=a.y;o[2]=a.z;o[3]=a.w;o[4]=b.x;o[5]=b.y;o[6]=b.z;o[7]=b.w;
  } else {
    uint4 u = *(const uint4*)((const ushort*)p + i);
    unsigned w0=u.x,w1=u.y,w2=u.z,w3=u.w;
    o[0]=__uint_as_float(w0<<16); o[1]=__uint_as_float(w0&0xFFFF0000u);
    o[2]=__uint_as_float(w1<<16); o[3]=__uint_as_float(w1&0xFFFF0000u);
    o[4]=__uint_as_float(w2<<16); o[5]=__uint_as_float(w2&0xFFFF0000u);
    o[6]=__uint_as_float(w3<<16); o[7]=__uint_as_float(w3&0xFFFF0000u);
  }
}
__device__ __forceinline__ uint4 pack8(const ushort* h){
  uint4 u;
  u.x = (unsigned)h[0] | ((unsigned)h[1]<<16);
  u.y = (unsigned)h[2] | ((unsigned)h[3]<<16);
  u.z = (unsigned)h[4] | ((unsigned)h[5]<<16);
  u.w = (unsigned)h[6] | ((unsigned)h[7]<<16);
  return u;
}

__global__ void init_kernel(int* wsI){ if (threadIdx.x<4) wsI[threadIdx.x]=0; }

__global__ __launch_bounds__(256) void detect_kernel(int* wsI, const uint4* wih4){
  int c=0;
  for (int i = blockIdx.x*blockDim.x + threadIdx.x; i < 32768; i += gridDim.x*blockDim.x){
    uint4 u = wih4[i];
    unsigned w[4] = {u.x,u.y,u.z,u.w};
    #pragma unroll
    for (int j=0;j<4;j++){
      if ((w[j] & 0x7F80u) == 0x7F80u) c++;
      if ((w[j] & 0x7F800000u) == 0x7F800000u) c++;
    }
  }
  #pragma unroll
  for (int o=32;o>0;o>>=1) c += __shfl_xor(c,o,64);
  if ((threadIdx.x&63)==0 && c) atomicAdd(&wsI[1], c);
}

// ---- zpe: fused z1 (blocks 0..3) + prep (4..131) + ewc (132..157) ----
__global__ __launch_bounds__(256) void zpe_kernel(
    float* __restrict__ wsf, const void* W_ih, const void* b_ih, const void* b_hh,
    const void* bt, const void* linit, const void* W_hh, const void* Wc,
    const void* Wt, const void* emb, const void* bc)
{
  const int f32 = ((const int*)wsf)[1] != 0;
  const int bid = blockIdx.x;
  const int tid = threadIdx.x;

  if (bid < 4){
    __shared__ float sx[256];
    int r = bid*256 + tid;
    sx[tid] = ldin(linit, tid, f32);
    __syncthreads();
    float a = ldin(b_ih, r, f32) + ldin(b_hh, r, f32);
    wsf[OFF_BSUM + r] = a;
    float z = a;
    #pragma unroll 8
    for (int k=0;k<256;k+=8){
      float w[8]; ld8(W_ih, r*256+k, f32, w);
      #pragma unroll
      for (int j=0;j<8;j++) z += w[j]*sx[k+j];
    }
    wsf[OFF_Z1 + r] = z;
    if (bid==0) wsf[OFF_BTF + tid] = ldin(bt, tid, f32);
  } else if (bid < 132){
    ushort* FWIH = (ushort*)(wsf + OFF_FRAG);
    ushort* FWHH = FWIH + 262144;
    ushort* FWC1 = FWHH + 262144;
    ushort* FWT  = FWC1 + 65536;
    int t0 = (bid-4)*256 + tid;   // 0..32767
    {
      int i = t0;
      int c = i >> 6, L = i & 63;
      int mt = c>>3, ks = c&7;
      int m = (mt<<4) | (L&15);
      int k0 = (ks<<5) + ((L>>4)<<3);
      float w[8]; ushort h[8];
      ld8(W_ih, m*256+k0, f32, w);
      #pragma unroll
      for (int j=0;j<8;j++) h[j]=f2b(w[j]);
      *(uint4*)&FWIH[(c<<9)+(L<<3)] = pack8(h);
      ld8(W_hh, m*256+k0, f32, w);
      #pragma unroll
      for (int j=0;j<8;j++) h[j]=f2b(w[j]);
      *(uint4*)&FWHH[(c<<9)+(L<<3)] = pack8(h);
    }
    if (t0 < 8192){
      int i = t0;
      int c = i >> 6, L = i & 63;
      int mt = c>>3, ks = c&7;
      int m = (mt<<4) | (L&15);
      int k0 = (ks<<5) + ((L>>4)<<3);
      float w[8]; ushort h[8];
      ld8(Wc, m*512+k0, f32, w);
      #pragma unroll
      for (int j=0;j<8;j++) h[j]=f2b(w[j]);
      *(uint4*)&FWC1[(c<<9)+(L<<3)] = pack8(h);
      ld8(Wt, m*256+k0, f32, w);
      #pragma unroll
      for (int j=0;j<8;j++) h[j]=f2b(w[j]);
      *(uint4*)&FWT[(c<<9)+(L<<3)] = pack8(h);
    }
  } else {
    __shared__ float se[256];
    int v = bid - 132, i = tid;
    se[i] = ldin(emb, v*256+i, f32);
    __syncthreads();
    float a = ldin(bc, i, f32);
    #pragma unroll 8
    for (int k=0;k<256;k+=8){
      float w[8]; ld8(Wc, i*512+256+k, f32, w);
      #pragma unroll
      for (int j=0;j<8;j++) a += w[j]*se[k+j];
    }
    wsf[OFF_EWC + v*256 + i] = a;
  }
}

// ---- hh1x: derives h1 from Z1 in-block (h1 folded in) ----
__global__ __launch_bounds__(256) void hh1x_kernel(float* __restrict__ wsf, const void* W_hh, const void* Wc){
  const int f32 = ((const int*)wsf)[1] != 0;
  __shared__ float sh1[256];
  int tid = threadIdx.x;
  float zi0 = wsf[OFF_Z1+tid], zg0 = wsf[OFF_Z1+512+tid], zo0 = wsf[OFF_Z1+768+tid];
  float c1 = sigmf(zi0)*tanhfast(zg0);
  float h1 = sigmf(zo0)*tanhfast(c1);
  sh1[tid] = h1;
  __syncthreads();
  if (blockIdx.x < 4){
    int r = blockIdx.x*256 + tid;
    float z = wsf[OFF_BSUM + r];
    #pragma unroll 8
    for (int k=0;k<256;k+=8){
      float w[8]; ld8(W_hh, r*256+k, f32, w);
      #pragma unroll
      for (int j=0;j<8;j++) z += w[j]*sh1[k+j];
    }
    wsf[OFF_HH1 + r] = z;
  } else {
    wsf[OFF_H1 + tid] = h1;
    wsf[OFF_C1 + tid] = c1;
    float a = 0.f;
    #pragma unroll 8
    for (int k=0;k<256;k+=8){
      float w[8]; ld8(Wc, tid*512+k, f32, w);
      #pragma unroll
      for (int j=0;j<8;j++) a += w[j]*sh1[k+j];
    }
    wsf[OFF_WCH1 + tid] = a;
    ushort* SCB = (ushort*)(wsf + OFF_SCB);
    #pragma unroll 1
    for (int v32=0; v32<32; v32++){
      int v = v32 < NVOCAB ? v32 : NVOCAB-1;
      SCB[v32*256 + tid] = f2b(a + wsf[OFF_EWC + v*256 + tid]);
    }
  }
}

// ---- tag8: tag = Wt@scomb + bt, log-softmax, out8 bf16 rows (26 vocab) ----
__global__ __launch_bounds__(256) void tag8_kernel(float* __restrict__ wsf){
  __shared__ float wred[4][16];
  const int tid=threadIdx.x, wv=tid>>6, lane=tid&63, ln15=lane&15, quad=lane>>4;
  const int nt = blockIdx.x;
  const ushort* FWT = (const ushort*)(wsf + OFF_FRAG) + 262144 + 262144 + 65536;
  const ushort* SCB = (const ushort*)(wsf + OFF_SCB);
  ushort* O8B = (ushort*)(wsf + OFF_O8B);
  const int row = nt*16 + ln15;

  f32x4 tg[4];
  #pragma unroll 1
  for (int p=0; p<4; p++){
    const int mt = wv*4 + p;
    tg[p] = (f32x4){0.f,0.f,0.f,0.f};
    #pragma unroll
    for (int ks=0; ks<8; ks++){
      bf16x8 a = *(const bf16x8*)&FWT[((mt*8+ks)<<9) + (lane<<3)];
      bf16x8 b = *(const bf16x8*)&SCB[row*256 + ks*32 + quad*8];
      tg[p] = __builtin_amdgcn_mfma_f32_16x16x32_bf16(a, b, tg[p], 0,0,0);
    }
    float4 bt4 = *(const float4*)&wsf[OFF_BTF + mt*16 + quad*4];
    #pragma unroll
    for (int r=0; r<4; r++) tg[p][r] += ((const float*)&bt4)[r];
  }

  float mx = -3.0e38f;
  #pragma unroll
  for (int p=0; p<4; p++)
    #pragma unroll
    for (int r=0; r<4; r++) mx = fmaxf(mx, tg[p][r]);
  mx = fmaxf(mx, __shfl_xor(mx, 16, 64));
  mx = fmaxf(mx, __shfl_xor(mx, 32, 64));
  wred[wv][ln15] = mx;
  __syncthreads();
  float gmx = fmaxf(fmaxf(wred[0][ln15], wred[1][ln15]), fmaxf(wred[2][ln15], wred[3][ln15]));
  __syncthreads();
  float s = 0.f;
  #pragma unroll
  for (int p=0; p<4; p++)
    #pragma unroll
    for (int r=0; r<4; r++) s += __expf(tg[p][r] - gmx);
  s += __shfl_xor(s, 16, 64);
  s += __shfl_xor(s, 32, 64);
  wred[wv][ln15] = s;
  __syncthreads();
  float gs = (wred[0][ln15]+wred[1][ln15]) + (wred[2][ln15]+wred[3][ln15]);
  float lz = gmx + __logf(gs);

  #pragma unroll
  for (int p=0; p<4; p++){
    int m = (wv*4+p)*16 + quad*4;
    ushort ob[4];
    #pragma unroll
    for (int r=0; r<4; r++) ob[r] = f2b(tg[p][r] - lz);
    uint2 uu;
    uu.x = (unsigned)ob[0] | ((unsigned)ob[1]<<16);
    uu.y = (unsigned)ob[2] | ((unsigned)ob[3]<<16);
    *(uint2*)&O8B[row*256 + m] = uu;
  }
}

// ---- p8: P8[v] = W_ih @ out8[v] via MFMA ----
__global__ __launch_bounds__(64) void p8_kernel(float* __restrict__ wsf){
  const int nt = blockIdx.x >> 4, eb = blockIdx.x & 15;
  const int lane = threadIdx.x, ln15 = lane & 15, quad = lane >> 4;
  const ushort* FWIH = (const ushort*)(wsf + OFF_FRAG);
  const ushort* O8B  = (const ushort*)(wsf + OFF_O8B);
  const int row = nt*16 + ln15;

  f32x4 acc[4];
  #pragma unroll
  for (int g=0; g<4; g++) acc[g] = (f32x4){0.f,0.f,0.f,0.f};
  #pragma unroll
  for (int ks=0; ks<8; ks++){
    bf16x8 b = *(const bf16x8*)&O8B[row*256 + ks*32 + quad*8];
    #pragma unroll
    for (int g=0; g<4; g++){
      int mt = g*16 + eb;
      bf16x8 a = *(const bf16x8*)&FWIH[((mt*8+ks)<<9) + (lane<<3)];
      acc[g] = __builtin_amdgcn_mfma_f32_16x16x32_bf16(a, b, acc[g], 0,0,0);
    }
  }
  if (row < NVOCAB){
    #pragma unroll
    for (int g=0; g<4; g++)
      *(float4*)&wsf[OFF_P8 + row*1024 + g*256 + eb*16 + quad*4] =
        (float4){acc[g][0], acc[g][1], acc[g][2], acc[g][3]};
  }
}

// ---- t2 table: (h2,c2)[a] = gate(hh1 + P8[a], cp=C1), a<26 ----
__global__ __launch_bounds__(256) void t2tab_kernel(float* __restrict__ wsf){
  int a = blockIdx.x, e = threadIdx.x;
  const float* P8a = wsf + OFF_P8 + (size_t)a*1024;
  float zi = wsf[OFF_HH1+e]     + P8a[e];
  float zf = wsf[OFF_HH1+256+e] + P8a[256+e];
  float zg = wsf[OFF_HH1+512+e] + P8a[512+e];
  float zo = wsf[OFF_HH1+768+e] + P8a[768+e];
  float cn = sigmf(zf)*wsf[OFF_C1+e] + sigmf(zi)*tanhfast(zg);
  ((ushort*)(wsf+OFF_H2B))[a*256+e] = f2b(sigmf(zo)*tanhfast(cn));
  wsf[OFF_C2T + a*256 + e] = cn;
}

// ---- hhmat: Out[r] = bsum + W_hh @ Hrows[r]  (MFMA, eb-sliced) ----
__global__ __launch_bounds__(64) void hhmat_kernel(
    float* __restrict__ wsf, const ushort* __restrict__ Hrows,
    float* __restrict__ Out, int R)
{
  const int nt = blockIdx.x >> 4, eb = blockIdx.x & 15;
  const int lane = threadIdx.x, ln15 = lane & 15, quad = lane >> 4;
  const ushort* FWHH = (const ushort*)(wsf + OFF_FRAG) + 262144;
  int row = nt*16 + ln15;
  int rowc = row < R ? row : R-1;

  f32x4 acc[4];
  #pragma unroll
  for (int g=0; g<4; g++) acc[g] = (f32x4){0.f,0.f,0.f,0.f};
  #pragma unroll
  for (int ks=0; ks<8; ks++){
    bf16x8 b = *(const bf16x8*)&Hrows[rowc*256 + ks*32 + quad*8];
    #pragma unroll
    for (int g=0; g<4; g++){
      int mt = g*16 + eb;
      bf16x8 a = *(const bf16x8*)&FWHH[((mt*8+ks)<<9) + (lane<<3)];
      acc[g] = __builtin_amdgcn_mfma_f32_16x16x32_bf16(a, b, acc[g], 0,0,0);
    }
  }
  if (row < R){
    #pragma unroll
    for (int g=0; g<4; g++){
      int m = g*256 + eb*16 + quad*4;
      float4 bs = *(const float4*)&wsf[OFF_BSUM + m];
      *(float4*)&Out[(size_t)row*1024 + m] =
        (float4){acc[g][0]+bs.x, acc[g][1]+bs.y, acc[g][2]+bs.z, acc[g][3]+bs.w};
    }
  }
}

// ---- t3 table: (h3,c3)[a*26+b] = gate(HH2A[a] + P8[b], cp=C2[a]) ----
__global__ __launch_bounds__(256) void t3tab_kernel(float* __restrict__ wsf){
  int p = blockIdx.x;
  int a = p / 26, b = p - a*26;
  int e = threadIdx.x;
  const float* HA = wsf + OFF_HH2A + (size_t)a*1024;
  const float* PB = wsf + OFF_P8   + (size_t)b*1024;
  float zi = HA[e]     + PB[e];
  float zf = HA[256+e] + PB[256+e];
  float zg = HA[512+e] + PB[512+e];
  float zo = HA[768+e] + PB[768+e];
  float cn = sigmf(zf)*wsf[OFF_C2T + a*256 + e] + sigmf(zi)*tanhfast(zg);
  ((ushort*)(wsf+OFF_H3B))[p*256+e] = f2b(sigmf(zo)*tanhfast(cn));
  wsf[OFF_C3T + p*256 + e] = cn;
}

// ---- l7f: fully fused L7 per-node kernel (full-row blocks of 16 nodes).
// Staging: serial-16, all 256 threads on one node/iter (round-7 proven form). ----
__global__ __launch_bounds__(256) void l7f_kernel(
    const float* __restrict__ wsf, const int* __restrict__ idents,
    ushort* __restrict__ OutNext)
{
  __shared__ __align__(16) ushort HbL[16*STR];   // h4, reused for comb
  __shared__ __align__(16) ushort H5L[16*STR];
  __shared__ float C4L[16*264];
  __shared__ float wred[4][16];
  const int tid=threadIdx.x, wv=tid>>6, lane=tid&63, ln15=lane&15, quad=lane>>4;
  const ushort* FWHH = (const ushort*)(wsf + OFF_FRAG) + 262144;
  const ushort* FWC1 = FWHH + 262144;
  const ushort* FWT  = FWC1 + 65536;
  const float*  EWcP = wsf + OFF_EWC;
  const int nb = blockIdx.x*16;

  #pragma unroll 2
  for (int i=0; i<16; i++){
    const int ib4 = 21845 + (nb+i)*4;
    const int ia = idents[ib4], ibb = idents[ib4+1], icc = idents[ib4+2];
    const int pp = ia*26 + ibb;
    const float* HA = wsf + OFF_HH3 + (size_t)pp*1024;
    const float* PB = wsf + OFF_P8  + (size_t)icc*1024;
    const int e = tid;
    float zi = HA[e]     + PB[e];
    float zf = HA[256+e] + PB[256+e];
    float zg = HA[512+e] + PB[512+e];
    float zo = HA[768+e] + PB[768+e];
    float cn = sigmf(zf)*wsf[OFF_C3T + (size_t)pp*256 + e] + sigmf(zi)*tanhfast(zg);
    C4L[i*264 + e] = cn;
    HbL[i*STR + e] = f2b(sigmf(zo)*tanhfast(cn));
  }
  __syncthreads();

  const int node = nb + ln15;
  const int idd = idents[21845 + node*4 + 3];
  const float* PD = wsf + OFF_P8 + (size_t)idd*1024;

  #pragma unroll 1
  for (int p=0; p<4; p++){
    const int eb = wv*4 + p;
    f32x4 acc[4];
    #pragma unroll
    for (int g=0; g<4; g++) acc[g] = (f32x4){0.f,0.f,0.f,0.f};
    #pragma unroll
    for (int ks=0; ks<8; ks++){
      bf16x8 b = *(const bf16x8*)&HbL[ln15*STR + ks*32 + quad*8];
      #pragma unroll
      for (int g=0; g<4; g++){
        bf16x8 a = *(const bf16x8*)&FWHH[(((g*16+eb)*8+ks)<<9) + (lane<<3)];
        acc[g] = __builtin_amdgcn_mfma_f32_16x16x32_bf16(a, b, acc[g], 0,0,0);
      }
    }
    const int e0 = eb*16 + quad*4;
    float4 bs0 = *(const float4*)&wsf[OFF_BSUM +       e0];
    float4 bs1 = *(const float4*)&wsf[OFF_BSUM + 256 + e0];
    float4 bs2 = *(const float4*)&wsf[OFF_BSUM + 512 + e0];
    float4 bs3 = *(const float4*)&wsf[OFF_BSUM + 768 + e0];
    float4 d0 = *(const float4*)&PD[      e0];
    float4 d1 = *(const float4*)&PD[256 + e0];
    float4 d2 = *(const float4*)&PD[512 + e0];
    float4 d3 = *(const float4*)&PD[768 + e0];
    float4 cp4 = *(const float4*)&C4L[ln15*264 + e0];
    ushort hb[4];
    #pragma unroll
    for (int r=0; r<4; r++){
      float zi = acc[0][r] + ((const float*)&bs0)[r] + ((const float*)&d0)[r];
      float zf = acc[1][r] + ((const float*)&bs1)[r] + ((const float*)&d1)[r];
      float zg = acc[2][r] + ((const float*)&bs2)[r] + ((const float*)&d2)[r];
      float zo = acc[3][r] + ((const float*)&bs3)[r] + ((const float*)&d3)[r];
      float cn = sigmf(zf)*((const float*)&cp4)[r] + sigmf(zi)*tanhfast(zg);
      hb[r] = f2b(sigmf(zo)*tanhfast(cn));
    }
    uint2 uu;
    uu.x = (unsigned)hb[0] | ((unsigned)hb[1]<<16);
    uu.y = (unsigned)hb[2] | ((unsigned)hb[3]<<16);
    *(uint2*)&H5L[ln15*STR + e0] = uu;
  }
  __syncthreads();

  const int myid = idents[5461 + node];
  #pragma unroll 1
  for (int p=0; p<4; p++){
    const int mt = wv*4 + p;
    f32x4 ac = (f32x4){0.f,0.f,0.f,0.f};
    #pragma unroll
    for (int ks=0; ks<8; ks++){
      bf16x8 a = *(const bf16x8*)&FWC1[((mt*8+ks)<<9) + (lane<<3)];
      bf16x8 b = *(const bf16x8*)&H5L[ln15*STR + ks*32 + quad*8];
      ac = __builtin_amdgcn_mfma_f32_16x16x32_bf16(a, b, ac, 0,0,0);
    }
    float4 ew = *(const float4*)&EWcP[(size_t)myid*256 + mt*16 + quad*4];
    ushort cb[4];
    #pragma unroll
    for (int r=0; r<4; r++) cb[r] = f2b(ac[r] + ((const float*)&ew)[r]);
    uint2 uu;
    uu.x = (unsigned)cb[0] | ((unsigned)cb[1]<<16);
    uu.y = (unsigned)cb[2] | ((unsigned)cb[3]<<16);
    *(uint2*)&HbL[ln15*STR + mt*16 + quad*4] = uu;
  }
  __syncthreads();

  f32x4 tg[4];
  #pragma unroll 1
  for (int p=0; p<4; p++){
    const int mt = wv*4 + p;
    tg[p] = (f32x4){0.f,0.f,0.f,0.f};
    #pragma unroll
    for (int ks=0; ks<8; ks++){
      bf16x8 a = *(const bf16x8*)&FWT[((mt*8+ks)<<9) + (lane<<3)];
      bf16x8 b = *(const bf16x8*)&HbL[ln15*STR + ks*32 + quad*8];
      tg[p] = __builtin_amdgcn_mfma_f32_16x16x32_bf16(a, b, tg[p], 0,0,0);
    }
    float4 bt4 = *(const float4*)&wsf[OFF_BTF + mt*16 + quad*4];
    #pragma unroll
    for (int r=0; r<4; r++) tg[p][r] += ((const float*)&bt4)[r];
  }

  float mx = -3.0e38f;
  #pragma unroll
  for (int p=0; p<4; p++)
    #pragma unroll
    for (int r=0; r<4; r++) mx = fmaxf(mx, tg[p][r]);
  mx = fmaxf(mx, __shfl_xor(mx, 16, 64));
  mx = fmaxf(mx, __shfl_xor(mx, 32, 64));
  wred[wv][ln15] = mx;
  __syncthreads();
  float gmx = fmaxf(fmaxf(wred[0][ln15], wred[1][ln15]), fmaxf(wred[2][ln15], wred[3][ln15]));
  __syncthreads();
  float s = 0.f;
  #pragma unroll
  for (int p=0; p<4; p++)
    #pragma unroll
    for (int r=0; r<4; r++) s += __expf(tg[p][r] - gmx);
  s += __shfl_xor(s, 16, 64);
  s += __shfl_xor(s, 32, 64);
  wred[wv][ln15] = s;
  __syncthreads();
  float gs = (wred[0][ln15]+wred[1][ln15]) + (wred[2][ln15]+wred[3][ln15]);
  float lz = gmx + __logf(gs);

  #pragma unroll
  for (int p=0; p<4; p++){
    int m = (wv*4+p)*16 + quad*4;
    ushort ob[4];
    #pragma unroll
    for (int r=0; r<4; r++) ob[r] = f2b(tg[p][r] - lz);
    uint2 uu;
    uu.x = (unsigned)ob[0] | ((unsigned)ob[1]<<16);
    uu.y = (unsigned)ob[2] | ((unsigned)ob[3]<<16);
    *(uint2*)&OutNext[(size_t)node*256 + m] = uu;
  }
}

// ---- one LSTM t-step: eb-sliced, 64 thr (proven shape, VGPR ~52).
// SWZ=true (requires nTiles%8==0): all 16 eb-blocks of a node tile share
// bid%8 -> same XCD L2 (B rows fetched once, output lines merged). ----
template<bool FIRST, bool SWZ>
__global__ __launch_bounds__(64) void step_kernel(
    const float* __restrict__ wsf, const ushort* __restrict__ OutPrev,
    const ushort* __restrict__ Hin, ushort* __restrict__ Hout,
    float* __restrict__ Cbuf, int nNodes, int tm1)
{
  const int bid = blockIdx.x;
  int nt, eb;
  if (SWZ){
    const int xcd = bid & 7;
    const int j   = bid >> 3;
    eb = j & 15;
    nt = (j >> 4)*8 + xcd;
  } else {
    nt = bid >> 4;
    eb = bid & 15;
  }
  const int lane = threadIdx.x;
  const int ln15 = lane & 15;
  const int quad = lane >> 4;

  const ushort* FWIH = (const ushort*)(wsf + OFF_FRAG);
  const ushort* FWHH = FWIH + 262144;

  int node = nt*16 + ln15; if (node >= nNodes) node = nNodes-1;
  const int rowX = (node*4 + tm1) * 256;
  const int rowH = node * 256;

  f32x4 acc[4];
  #pragma unroll
  for (int g=0; g<4; g++) acc[g] = (f32x4){0.f,0.f,0.f,0.f};

  #pragma unroll
  for (int ks=0; ks<8; ks++){
    bf16x8 bx = *(const bf16x8*)&OutPrev[rowX + ks*32 + quad*8];
    bf16x8 bh;
    if (!FIRST) bh = *(const bf16x8*)&Hin[rowH + ks*32 + quad*8];
    #pragma unroll
    for (int g=0; g<4; g++){
      int mt = g*16 + eb;
      bf16x8 a = *(const bf16x8*)&FWIH[((mt*8+ks)<<9) + (lane<<3)];
      acc[g] = __builtin_amdgcn_mfma_f32_16x16x32_bf16(a, bx, acc[g], 0,0,0);
      if (!FIRST){
        bf16x8 a2 = *(const bf16x8*)&FWHH[((mt*8+ks)<<9) + (lane<<3)];
        acc[g] = __builtin_amdgcn_mfma_f32_16x16x32_bf16(a2, bh, acc[g], 0,0,0);
      }
    }
  }

  const float* baseP = wsf + (FIRST ? OFF_HH1 : OFF_BSUM);
  const int e0 = eb*16 + quad*4;
  float4 b0 = *(const float4*)&baseP[       e0];
  float4 b1 = *(const float4*)&baseP[ 256 + e0];
  float4 b2 = *(const float4*)&baseP[ 512 + e0];
  float4 b3 = *(const float4*)&baseP[ 768 + e0];
  float4 cp;
  if (FIRST) cp = *(const float4*)&wsf[OFF_C1 + e0];
  else       cp = *(const float4*)&Cbuf[rowH + e0];

  float cn4[4]; ushort hb[4];
  #pragma unroll
  for (int r=0; r<4; r++){
    float zi = acc[0][r] + ((const float*)&b0)[r];
    float zf = acc[1][r] + ((const float*)&b1)[r];
    float zg = acc[2][r] + ((const float*)&b2)[r];
    float zo = acc[3][r] + ((const float*)&b3)[r];
    float cn = sigmf(zf)*((const float*)&cp)[r] + sigmf(zi)*tanhfast(zg);
    cn4[r] = cn;
    hb[r] = f2b(sigmf(zo)*tanhfast(cn));
  }
  *(float4*)&Cbuf[rowH + e0] = (float4){cn4[0],cn4[1],cn4[2],cn4[3]};
  uint2 uu;
  uu.x = (unsigned)hb[0] | ((unsigned)hb[1]<<16);
  uu.y = (unsigned)hb[2] | ((unsigned)hb[3]<<16);
  *(uint2*)&Hout[rowH + e0] = uu;
}

// ---- epilogue for L6/L5: combine -> tag -> log-softmax -> out ----
__global__ __launch_bounds__(256) void fin_kernel(
    const float* __restrict__ wsf, const ushort* __restrict__ Hfin,
    const int* __restrict__ idents, int offL, int nNodes,
    ushort* __restrict__ OutNext)
{
  __shared__ __align__(16) ushort Clds[16*STR];
  __shared__ float wred[4][16];
  const int tid  = threadIdx.x;
  const int wv   = tid >> 6;
  const int lane = tid & 63;
  const int ln15 = lane & 15;
  const int quad = lane >> 4;
  const int nt   = blockIdx.x;

  const ushort* FWIH = (const ushort*)(wsf + OFF_FRAG);
  const ushort* FWC1 = FWIH + 262144 + 262144;
  const ushort* FWT  = FWC1 + 65536;
  const float*  EWcP = wsf + OFF_EWC;

  int node = nt*16 + ln15; if (node >= nNodes) node = nNodes-1;
  const int myid = idents[offL + node];
  const int rowH = node * 256;

  #pragma unroll 1
  for (int p=0; p<4; p++){
    const int mt = wv*4 + p;
    f32x4 ac = (f32x4){0.f,0.f,0.f,0.f};
    #pragma unroll
    for (int ks=0; ks<8; ks++){
      bf16x8 a = *(const bf16x8*)&FWC1[((mt*8+ks)<<9) + (lane<<3)];
      bf16x8 b = *(const bf16x8*)&Hfin[rowH + ks*32 + quad*8];
      ac = __builtin_amdgcn_mfma_f32_16x16x32_bf16(a, b, ac, 0,0,0);
    }
    float4 ew = *(const float4*)&EWcP[(size_t)myid*256 + mt*16 + quad*4];
    ushort cb[4];
    #pragma unroll
    for (int r=0; r<4; r++) cb[r] = f2b(ac[r] + ((const float*)&ew)[r]);
    uint2 uu;
    uu.x = (unsigned)cb[0] | ((unsigned)cb[1]<<16);
    uu.y = (unsigned)cb[2] | ((unsigned)cb[3]<<16);
    *(uint2*)&Clds[ln15*STR + mt*16 + quad*4] = uu;
  }
  __syncthreads();

  f32x4 tg[4];
  #pragma unroll 1
  for (int p=0; p<4; p++){
    const int mt = wv*4 + p;
    tg[p] = (f32x4){0.f,0.f,0.f,0.f};
    #pragma unroll
    for (int ks=0; ks<8; ks++){
      bf16x8 a = *(const bf16x8*)&FWT[((mt*8+ks)<<9) + (lane<<3)];
      bf16x8 b = *(const bf16x8*)&Clds[ln15*STR + ks*32 + quad*8];
      tg[p] = __builtin_amdgcn_mfma_f32_16x16x32_bf16(a, b, tg[p], 0,0,0);
    }
    float4 bt4 = *(const float4*)&wsf[OFF_BTF + mt*16 + quad*4];
    #pragma unroll
    for (int r=0; r<4; r++) tg[p][r] += ((const float*)&bt4)[r];
  }

  float mx = -3.0e38f;
  #pragma unroll
  for (int p=0; p<4; p++)
    #pragma unroll
    for (int r=0; r<4; r++) mx = fmaxf(mx, tg[p][r]);
  mx = fmaxf(mx, __shfl_xor(mx, 16, 64));
  mx = fmaxf(mx, __shfl_xor(mx, 32, 64));
  wred[wv][ln15] = mx;
  __syncthreads();
  float gmx = fmaxf(fmaxf(wred[0][ln15], wred[1][ln15]), fmaxf(wred[2][ln15], wred[3][ln15]));
  __syncthreads();
  float s = 0.f;
  #pragma unroll
  for (int p=0; p<4; p++)
    #pragma unroll
    for (int r=0; r<4; r++) s += __expf(tg[p][r] - gmx);
  s += __shfl_xor(s, 16, 64);
  s += __shfl_xor(s, 32, 64);
  wred[wv][ln15] = s;
  __syncthreads();
  float gs = (wred[0][ln15]+wred[1][ln15]) + (wred[2][ln15]+wred[3][ln15]);
  float lz = gmx + __logf(gs);

  int onode = nt*16 + ln15;
  if (onode < nNodes){
    #pragma unroll
    for (int p=0; p<4; p++){
      int m = (wv*4+p)*16 + quad*4;
      ushort ob[4];
      #pragma unroll
      for (int r=0; r<4; r++) ob[r] = f2b(tg[p][r] - lz);
      uint2 uu;
      uu.x = (unsigned)ob[0] | ((unsigned)ob[1]<<16);
      uu.y = (unsigned)ob[2] | ((unsigned)ob[3]<<16);
      *(uint2*)&OutNext[(size_t)onode*256 + m] = uu;
    }
  }
}

// ---- tailv: one whole level (n<=256) per launch. 16 nodes/block, 256 thr.
// 4 LSTM steps with DOUBLE-BUFFERED LDS h (no staging arrays, no race),
// p-loop unroll 1 (4 accumulators live — the proven step-kernel register
// shape), then combine -> tag -> log-softmax -> out. ----
template<bool FINAL>
__global__ __launch_bounds__(256) void tailv_kernel(
    const float* __restrict__ wsf, const ushort* __restrict__ OutPrev,
    const int* __restrict__ idents, int offL, int nNodes,
    ushort* __restrict__ OutNext, void* __restrict__ dout)
{
  __shared__ __align__(16) ushort Hl[2][16*STR];
  __shared__ __align__(16) ushort Cmb[16*STR];
  __shared__ float Cl[16*264];
  __shared__ float wred[4][16];
  const int tid=threadIdx.x, wv=tid>>6, lane=tid&63, ln15=lane&15, quad=lane>>4;
  const ushort* FWIH = (const ushort*)(wsf + OFF_FRAG);
  const ushort* FWHH = FWIH + 262144;
  const ushort* FWC1 = FWHH + 262144;
  const ushort* FWT  = FWC1 + 65536;
  const float*  EWcP = wsf + OFF_EWC;

  int node = blockIdx.x*16 + ln15; if (node >= nNodes) node = nNodes-1;

  // 4 LSTM steps; step t reads Hl[t&1], writes Hl[(t+1)&1]. Cl is
  // same-thread elementwise (read+write own slice) — no cross-thread hazard.
  #pragma unroll 1
  for (int t=0; t<4; t++){
    const int cur = t & 1, nxt = cur ^ 1;
    const int rowX = (node*4 + t)*256;
    #pragma unroll 1
    for (int p=0; p<4; p++){
      const int eb = wv*4 + p;
      f32x4 acc[4];
      #pragma unroll
      for (int g=0; g<4; g++) acc[g] = (f32x4){0.f,0.f,0.f,0.f};
      #pragma unroll
      for (int ks=0; ks<8; ks++){
        bf16x8 bx = *(const bf16x8*)&OutPrev[(size_t)rowX + ks*32 + quad*8];
        bf16x8 bh;
        if (t > 0) bh = *(const bf16x8*)&Hl[cur][ln15*STR + ks*32 + quad*8];
        #pragma unroll
        for (int g=0; g<4; g++){
          int mt = g*16 + eb;
          bf16x8 a = *(const bf16x8*)&FWIH[((mt*8+ks)<<9) + (lane<<3)];
          acc[g] = __builtin_amdgcn_mfma_f32_16x16x32_bf16(a, bx, acc[g], 0,0,0);
          if (t > 0){
            bf16x8 a2 = *(const bf16x8*)&FWHH[((mt*8+ks)<<9) + (lane<<3)];
            acc[g] = __builtin_amdgcn_mfma_f32_16x16x32_bf16(a2, bh, acc[g], 0,0,0);
          }
        }
      }
      const float* baseP = wsf + (t==0 ? OFF_HH1 : OFF_BSUM);
      const int e0 = eb*16 + quad*4;
      float4 b0 = *(const float4*)&baseP[       e0];
      float4 b1 = *(const float4*)&baseP[ 256 + e0];
      float4 b2 = *(const float4*)&baseP[ 512 + e0];
      float4 b3 = *(const float4*)&baseP[ 768 + e0];
      float4 cp;
      if (t==0) cp = *(const float4*)&wsf[OFF_C1 + e0];
      else      cp = *(const float4*)&Cl[ln15*264 + e0];
      float cn4[4]; ushort hb[4];
      #pragma unroll
      for (int r=0; r<4; r++){
        float zi = acc[0][r] + ((const float*)&b0)[r];
        float zf = acc[1][r] + ((const float*)&b1)[r];
        float zg = acc[2][r] + ((const float*)&b2)[r];
        float zo = acc[3][r] + ((const float*)&b3)[r];
        float cn = sigmf(zf)*((const float*)&cp)[r] + sigmf(zi)*tanhfast(zg);
        cn4[r] = cn;
        hb[r] = f2b(sigmf(zo)*tanhfast(cn));
      }
      *(float4*)&Cl[ln15*264 + e0] = (float4){cn4[0],cn4[1],cn4[2],cn4[3]};
      uint2 uu;
      uu.x = (unsigned)hb[0] | ((unsigned)hb[1]<<16);
      uu.y = (unsigned)hb[2] | ((unsigned)hb[3]<<16);
      *(uint2*)&Hl[nxt][ln15*STR + e0] = uu;
    }
    __syncthreads();   // Hl[nxt] complete before step t+1 reads it
  }
  // final h is in Hl[0] (t=3 wrote nxt=0)

  // combine = Wc1@h + EWc[id]
  const int myid = idents[offL + node];
  #pragma unroll 1
  for (int p=0; p<4; p++){
    const int mt = wv*4 + p;
    f32x4 ac = (f32x4){0.f,0.f,0.f,0.f};
    #pragma unroll
    for (int ks=0; ks<8; ks++){
      bf16x8 a = *(const bf16x8*)&FWC1[((mt*8+ks)<<9) + (lane<<3)];
      bf16x8 b = *(const bf16x8*)&Hl[0][ln15*STR + ks*32 + quad*8];
      ac = __builtin_amdgcn_mfma_f32_16x16x32_bf16(a, b, ac, 0,0,0);
    }
    float4 ew = *(const float4*)&EWcP[(size_t)myid*256 + mt*16 + quad*4];
    ushort cb[4];
    #pragma unroll
    for (int r=0; r<4; r++) cb[r] = f2b(ac[r] + ((const float*)&ew)[r]);
    uint2 uu;
    uu.x = (unsigned)cb[0] | ((unsigned)cb[1]<<16);
    uu.y = (unsigned)cb[2] | ((unsigned)cb[3]<<16);
    *(uint2*)&Cmb[ln15*STR + mt*16 + quad*4] = uu;
  }
  __syncthreads();

  // tag = Wt@comb + bt, log-softmax over 256
  f32x4 tg[4];
  #pragma unroll 1
  for (int p=0; p<4; p++){
    const int mt = wv*4 + p;
    tg[p] = (f32x4){0.f,0.f,0.f,0.f};
    #pragma unroll
    for (int ks=0; ks<8; ks++){
      bf16x8 a = *(const bf16x8*)&FWT[((mt*8+ks)<<9) + (lane<<3)];
      bf16x8 b = *(const bf16x8*)&Cmb[ln15*STR + ks*32 + quad*8];
      tg[p] = __builtin_amdgcn_mfma_f32_16x16x32_bf16(a, b, tg[p], 0,0,0);
    }
    float4 bt4 = *(const float4*)&wsf[OFF_BTF + mt*16 + quad*4];
    #pragma unroll
    for (int r=0; r<4; r++) tg[p][r] += ((const float*)&bt4)[r];
  }

  float mx = -3.0e38f;
  #pragma unroll
  for (int p=0; p<4; p++)
    #pragma unroll
    for (int r=0; r<4; r++) mx = fmaxf(mx, tg[p][r]);
  mx = fmaxf(mx, __shfl_xor(mx, 16, 64));
  mx = fmaxf(mx, __shfl_xor(mx, 32, 64));
  wred[wv][ln15] = mx;
  __syncthreads();
  float gmx = fmaxf(fmaxf(wred[0][ln15], wred[1][ln15]), fmaxf(wred[2][ln15], wred[3][ln15]));
  __syncthreads();
  float s = 0.f;
  #pragma unroll
  for (int p=0; p<4; p++)
    #pragma unroll
    for (int r=0; r<4; r++) s += __expf(tg[p][r] - gmx);
  s += __shfl_xor(s, 16, 64);
  s += __shfl_xor(s, 32, 64);
  wred[wv][ln15] = s;
  __syncthreads();
  float gs = (wred[0][ln15]+wred[1][ln15]) + (wred[2][ln15]+wred[3][ln15]);
  float lz = gmx + __logf(gs);

  if (FINAL){
    if (ln15 == 0){
      const int f32o = ((const int*)wsf)[1] != 0;
      #pragma unroll
      for (int p=0; p<4; p++){
        #pragma unroll
        for (int r=0; r<4; r++){
          int m = (wv*4+p)*16 + quad*4 + r;
          float v = tg[p][r] - lz;
          if (f32o) ((float*)dout)[m] = v;
          else      ((ushort*)dout)[m] = f2b(v);
        }
      }
    }
    return;
  }
  int onode = blockIdx.x*16 + ln15;
  if (onode < nNodes){
    #pragma unroll
    for (int p=0; p<4; p++){
      int m = (wv*4+p)*16 + quad*4;
      ushort ob[4];
      #pragma unroll
      for (int r=0; r<4; r++) ob[r] = f2b(tg[p][r] - lz);
      uint2 uu;
      uu.x = (unsigned)ob[0] | ((unsigned)ob[1]<<16);
      uu.y = (unsigned)ob[2] | ((unsigned)ob[3]<<16);
      *(uint2*)&OutNext[(size_t)onode*256 + m] = uu;
    }
  }
}

extern "C" void kernel_launch(void* const* d_in, const int* in_sizes, int n_in,
                              void* d_out, int out_size, void* d_ws, size_t ws_size,
                              hipStream_t stream)
{
  (void)in_sizes; (void)n_in; (void)out_size; (void)ws_size;
  const int* idents = (const int*)d_in[0];
  const void* emb   = d_in[1];
  const void* W_ih  = d_in[2];
  const void* W_hh  = d_in[3];
  const void* b_ih  = d_in[4];
  const void* b_hh  = d_in[5];
  const void* Wc    = d_in[6];
  const void* bc    = d_in[7];
  const void* Wt    = d_in[8];
  const void* bt    = d_in[9];
  const void* linit = d_in[10];

  float* wsf = (float*)d_ws;
  ushort* slabA = (ushort*)(wsf + OFF_SLABS);
  ushort* slabB = slabA + (size_t)16384*256;
  ushort* Hb0   = slabB + (size_t)4096*256;      // 4096 rows (L6-sized)
  ushort* Hb1   = Hb0 + (size_t)4096*256;
  float*  Cb    = (float*)(Hb1 + (size_t)4096*256);

  init_kernel  <<<1, 64, 0, stream>>>((int*)d_ws);
  detect_kernel<<<16, 256, 0, stream>>>((int*)d_ws, (const uint4*)W_ih);
  zpe_kernel   <<<158, 256, 0, stream>>>(wsf, W_ih, b_ih, b_hh, bt, linit, W_hh, Wc, Wt, emb, bc);
  hh1x_kernel  <<<5, 256, 0, stream>>>(wsf, W_hh, Wc);
  tag8_kernel  <<<2, 256, 0, stream>>>(wsf);
  p8_kernel    <<<32, 64, 0, stream>>>(wsf);

  // L7 child-prefix tables (parallel, proven)
  t2tab_kernel <<<NVOCAB, 256, 0, stream>>>(wsf);
  hhmat_kernel <<<32, 64, 0, stream>>>(wsf, (const ushort*)(wsf+OFF_H2B), wsf+OFF_HH2A, NVOCAB);
  t3tab_kernel <<<NVOCAB*NVOCAB, 256, 0, stream>>>(wsf);
  hhmat_kernel <<<((NVOCAB*NVOCAB+15)/16)*16, 64, 0, stream>>>(wsf, (const ushort*)(wsf+OFF_H3B), wsf+OFF_HH3, NVOCAB*NVOCAB);

  // L7: single fused kernel (h4 -> t5 -> combine -> tag -> softmax)
  l7f_kernel   <<<1024, 256, 0, stream>>>(wsf, idents, slabA);

  // L6 (4096) and L5 (1024): eb-sliced steps with XCD swizzle + fin
  step_kernel<true ,true><<<4096, 64, 0, stream>>>(wsf, slabA, nullptr, Hb1, Cb, 4096, 0);
  step_kernel<false,true><<<4096, 64, 0, stream>>>(wsf, slabA, Hb1, Hb0, Cb, 4096, 1);
  step_kernel<false,true><<<4096, 64, 0, stream>>>(wsf, slabA, Hb0, Hb1, Cb, 4096, 2);
  step_kernel<false,true><<<4096, 64, 0, stream>>>(wsf, slabA, Hb1, Hb0, Cb, 4096, 3);
  fin_kernel<<<256, 256, 0, stream>>>(wsf, Hb0, idents, 1365, 4096, slabB);
  step_kernel<true ,true><<<1024, 64, 0, stream>>>(wsf, slabB, nullptr, Hb1, Cb, 1024, 0);
  step_kernel<false,true><<<1024, 64, 0, stream>>>(wsf, slabB, Hb1, Hb0, Cb, 1024, 1);
  step_kernel<false,true><<<1024, 64, 0, stream>>>(wsf, slabB, Hb0, Hb1, Cb, 1024, 2);
  step_kernel<false,true><<<1024, 64, 0, stream>>>(wsf, slabB, Hb1, Hb0, Cb, 1024, 3);
  fin_kernel<<<64, 256, 0, stream>>>(wsf, Hb0, idents, 341, 1024, slabA);

  // L4..L0: one tailv launch per level (4 steps + fin fused, state in LDS)
  tailv_kernel<false><<<16, 256, 0, stream>>>(wsf, slabA, idents, 85, 256, slabB, nullptr);
  tailv_kernel<false><<< 4, 256, 0, stream>>>(wsf, slabB, idents, 21,  64, slabA, nullptr);
  tailv_kernel<false><<< 1, 256, 0, stream>>>(wsf, slabA, idents,  5,  16, slabB, nullptr);
  tailv_kernel<false><<< 1, 256, 0, stream>>>(wsf, slabB, idents,  1,   4, slabA, nullptr);
  tailv_kernel<true ><<< 1, 256, 0, stream>>>(wsf, slabA, idents,  0,   1, nullptr, d_out);
}

// Round 10
// 834.513 us; speedup vs baseline: 1.1665x; 1.1665x over previous
//
#include <hip/hip_runtime.h>
#include <hip/hip_bf16.h>
#include <hip/hip_cooperative_groups.h>
#include <cstdint>
#include <cstddef>

namespace cg = cooperative_groups;

typedef __hip_bfloat16 bf16;
typedef unsigned short ushort;
typedef __attribute__((ext_vector_type(8))) short bf16x8;
typedef __attribute__((ext_vector_type(4))) float f32x4;

#define HDIM 256
#define NVOCAB 26
#define STR 264

// ---- workspace layout (float offsets) ----
#define OFF_BSUM  16
#define OFF_Z1    (OFF_BSUM+1024)
#define OFF_HH1   (OFF_Z1+1024)
#define OFF_H1    (OFF_HH1+1024)
#define OFF_C1    (OFF_H1+256)
#define OFF_WCH1  (OFF_C1+256)
#define OFF_BTF   (OFF_WCH1+256)
#define OFF_EWC   (OFF_BTF+256)          // [26][256] f32
#define OFF_P8    (OFF_EWC+6656)         // [26][1024] f32
#define OFF_SCB   (OFF_P8+26624)         // [32][256] ushort (scomb bf16)
#define OFF_O8B   (OFF_SCB+4096)         // [32][256] ushort (out8 bf16)
#define OFF_H2B   (OFF_O8B+4096)         // [32][256] ushort (h2 per child0-id)
#define OFF_C2T   (OFF_H2B+4096)         // [32][256] f32
#define OFF_HH2A  (OFF_C2T+8192)         // [32][1024] f32 (bsum + W_hh@h2)
#define OFF_H3B   (OFF_HH2A+32768)       // [704][256] ushort (h3 per (id0,id1))
#define OFF_C3T   (OFF_H3B+90112)        // [704][256] f32
#define OFF_HH3   (OFF_C3T+180224)       // [704][1024] f32 (bsum + W_hh@h3)
#define OFF_FRAG  (OFF_HH3+720896)       // ushort frag tables
#define OFF_SLABS (OFF_FRAG+327680)

__device__ __forceinline__ float sigmf(float x){ return 1.0f/(1.0f+__expf(-x)); }
__device__ __forceinline__ float tanhfast(float x){ return 1.0f - 2.0f/(__expf(2.0f*x)+1.0f); }
__device__ __forceinline__ ushort f2b(float x){ bf16 h = __float2bfloat16(x); return *(ushort*)&h; }
__device__ __forceinline__ float ldin(const void* p, int i, int f32){
  if (f32) return ((const float*)p)[i];
  unsigned int w = ((unsigned int)((const ushort*)p)[i]) << 16;
  return __uint_as_float(w);
}
__device__ __forceinline__ void ld8(const void* p, int i, int f32, float* o){
  if (f32){
    float4 a = *(const float4*)((const float*)p + i);
    float4 b = *(const float4*)((const float*)p + i + 4);
    o[0]=a.x;o[1]=a.y;o[2]=a.z;o[3]=a.w;o[4]=b.x;o[5]=b.y;o[6]=b.z;o[7]=b.w;
  } else {
    uint4 u = *(const uint4*)((const ushort*)p + i);
    unsigned w0=u.x,w1=u.y,w2=u.z,w3=u.w;
    o[0]=__uint_as_float(w0<<16); o[1]=__uint_as_float(w0&0xFFFF0000u);
    o[2]=__uint_as_float(w1<<16); o[3]=__uint_as_float(w1&0xFFFF0000u);
    o[4]=__uint_as_float(w2<<16); o[5]=__uint_as_float(w2&0xFFFF0000u);
    o[6]=__uint_as_float(w3<<16); o[7]=__uint_as_float(w3&0xFFFF0000u);
  }
}
__device__ __forceinline__ uint4 pack8(const ushort* h){
  uint4 u;
  u.x = (unsigned)h[0] | ((unsigned)h[1]<<16);
  u.y = (unsigned)h[2] | ((unsigned)h[3]<<16);
  u.z = (unsigned)h[4] | ((unsigned)h[5]<<16);
  u.w = (unsigned)h[6] | ((unsigned)h[7]<<16);
  return u;
}

__global__ void init_kernel(int* wsI){ if (threadIdx.x<4) wsI[threadIdx.x]=0; }

__global__ __launch_bounds__(256) void detect_kernel(int* wsI, const uint4* wih4){
  int c=0;
  for (int i = blockIdx.x*blockDim.x + threadIdx.x; i < 32768; i += gridDim.x*blockDim.x){
    uint4 u = wih4[i];
    unsigned w[4] = {u.x,u.y,u.z,u.w};
    #pragma unroll
    for (int j=0;j<4;j++){
      if ((w[j] & 0x7F80u) == 0x7F80u) c++;
      if ((w[j] & 0x7F800000u) == 0x7F800000u) c++;
    }
  }
  #pragma unroll
  for (int o=32;o>0;o>>=1) c += __shfl_xor(c,o,64);
  if ((threadIdx.x&63)==0 && c) atomicAdd(&wsI[1], c);
}

// ---- zpe: fused z1 (blocks 0..3) + prep (4..131) + ewc (132..157) ----
__global__ __launch_bounds__(256) void zpe_kernel(
    float* __restrict__ wsf, const void* W_ih, const void* b_ih, const void* b_hh,
    const void* bt, const void* linit, const void* W_hh, const void* Wc,
    const void* Wt, const void* emb, const void* bc)
{
  const int f32 = ((const int*)wsf)[1] != 0;
  const int bid = blockIdx.x;
  const int tid = threadIdx.x;

  if (bid < 4){
    __shared__ float sx[256];
    int r = bid*256 + tid;
    sx[tid] = ldin(linit, tid, f32);
    __syncthreads();
    float a = ldin(b_ih, r, f32) + ldin(b_hh, r, f32);
    wsf[OFF_BSUM + r] = a;
    float z = a;
    #pragma unroll 8
    for (int k=0;k<256;k+=8){
      float w[8]; ld8(W_ih, r*256+k, f32, w);
      #pragma unroll
      for (int j=0;j<8;j++) z += w[j]*sx[k+j];
    }
    wsf[OFF_Z1 + r] = z;
    if (bid==0) wsf[OFF_BTF + tid] = ldin(bt, tid, f32);
  } else if (bid < 132){
    ushort* FWIH = (ushort*)(wsf + OFF_FRAG);
    ushort* FWHH = FWIH + 262144;
    ushort* FWC1 = FWHH + 262144;
    ushort* FWT  = FWC1 + 65536;
    int t0 = (bid-4)*256 + tid;   // 0..32767
    {
      int i = t0;
      int c = i >> 6, L = i & 63;
      int mt = c>>3, ks = c&7;
      int m = (mt<<4) | (L&15);
      int k0 = (ks<<5) + ((L>>4)<<3);
      float w[8]; ushort h[8];
      ld8(W_ih, m*256+k0, f32, w);
      #pragma unroll
      for (int j=0;j<8;j++) h[j]=f2b(w[j]);
      *(uint4*)&FWIH[(c<<9)+(L<<3)] = pack8(h);
      ld8(W_hh, m*256+k0, f32, w);
      #pragma unroll
      for (int j=0;j<8;j++) h[j]=f2b(w[j]);
      *(uint4*)&FWHH[(c<<9)+(L<<3)] = pack8(h);
    }
    if (t0 < 8192){
      int i = t0;
      int c = i >> 6, L = i & 63;
      int mt = c>>3, ks = c&7;
      int m = (mt<<4) | (L&15);
      int k0 = (ks<<5) + ((L>>4)<<3);
      float w[8]; ushort h[8];
      ld8(Wc, m*512+k0, f32, w);
      #pragma unroll
      for (int j=0;j<8;j++) h[j]=f2b(w[j]);
      *(uint4*)&FWC1[(c<<9)+(L<<3)] = pack8(h);
      ld8(Wt, m*256+k0, f32, w);
      #pragma unroll
      for (int j=0;j<8;j++) h[j]=f2b(w[j]);
      *(uint4*)&FWT[(c<<9)+(L<<3)] = pack8(h);
    }
  } else {
    __shared__ float se[256];
    int v = bid - 132, i = tid;
    se[i] = ldin(emb, v*256+i, f32);
    __syncthreads();
    float a = ldin(bc, i, f32);
    #pragma unroll 8
    for (int k=0;k<256;k+=8){
      float w[8]; ld8(Wc, i*512+256+k, f32, w);
      #pragma unroll
      for (int j=0;j<8;j++) a += w[j]*se[k+j];
    }
    wsf[OFF_EWC + v*256 + i] = a;
  }
}

// ---- hh1x: derives h1 from Z1 in-block (h1 folded in) ----
__global__ __launch_bounds__(256) void hh1x_kernel(float* __restrict__ wsf, const void* W_hh, const void* Wc){
  const int f32 = ((const int*)wsf)[1] != 0;
  __shared__ float sh1[256];
  int tid = threadIdx.x;
  float zi0 = wsf[OFF_Z1+tid], zg0 = wsf[OFF_Z1+512+tid], zo0 = wsf[OFF_Z1+768+tid];
  float c1 = sigmf(zi0)*tanhfast(zg0);
  float h1 = sigmf(zo0)*tanhfast(c1);
  sh1[tid] = h1;
  __syncthreads();
  if (blockIdx.x < 4){
    int r = blockIdx.x*256 + tid;
    float z = wsf[OFF_BSUM + r];
    #pragma unroll 8
    for (int k=0;k<256;k+=8){
      float w[8]; ld8(W_hh, r*256+k, f32, w);
      #pragma unroll
      for (int j=0;j<8;j++) z += w[j]*sh1[k+j];
    }
    wsf[OFF_HH1 + r] = z;
  } else {
    wsf[OFF_H1 + tid] = h1;
    wsf[OFF_C1 + tid] = c1;
    float a = 0.f;
    #pragma unroll 8
    for (int k=0;k<256;k+=8){
      float w[8]; ld8(Wc, tid*512+k, f32, w);
      #pragma unroll
      for (int j=0;j<8;j++) a += w[j]*sh1[k+j];
    }
    wsf[OFF_WCH1 + tid] = a;
    ushort* SCB = (ushort*)(wsf + OFF_SCB);
    #pragma unroll 1
    for (int v32=0; v32<32; v32++){
      int v = v32 < NVOCAB ? v32 : NVOCAB-1;
      SCB[v32*256 + tid] = f2b(a + wsf[OFF_EWC + v*256 + tid]);
    }
  }
}

// ---- tag8: tag = Wt@scomb + bt, log-softmax, out8 bf16 rows (26 vocab) ----
__global__ __launch_bounds__(256) void tag8_kernel(float* __restrict__ wsf){
  __shared__ float wred[4][16];
  const int tid=threadIdx.x, wv=tid>>6, lane=tid&63, ln15=lane&15, quad=lane>>4;
  const int nt = blockIdx.x;
  const ushort* FWT = (const ushort*)(wsf + OFF_FRAG) + 262144 + 262144 + 65536;
  const ushort* SCB = (const ushort*)(wsf + OFF_SCB);
  ushort* O8B = (ushort*)(wsf + OFF_O8B);
  const int row = nt*16 + ln15;

  f32x4 tg[4];
  #pragma unroll 1
  for (int p=0; p<4; p++){
    const int mt = wv*4 + p;
    tg[p] = (f32x4){0.f,0.f,0.f,0.f};
    #pragma unroll
    for (int ks=0; ks<8; ks++){
      bf16x8 a = *(const bf16x8*)&FWT[((mt*8+ks)<<9) + (lane<<3)];
      bf16x8 b = *(const bf16x8*)&SCB[row*256 + ks*32 + quad*8];
      tg[p] = __builtin_amdgcn_mfma_f32_16x16x32_bf16(a, b, tg[p], 0,0,0);
    }
    float4 bt4 = *(const float4*)&wsf[OFF_BTF + mt*16 + quad*4];
    #pragma unroll
    for (int r=0; r<4; r++) tg[p][r] += ((const float*)&bt4)[r];
  }

  float mx = -3.0e38f;
  #pragma unroll
  for (int p=0; p<4; p++)
    #pragma unroll
    for (int r=0; r<4; r++) mx = fmaxf(mx, tg[p][r]);
  mx = fmaxf(mx, __shfl_xor(mx, 16, 64));
  mx = fmaxf(mx, __shfl_xor(mx, 32, 64));
  wred[wv][ln15] = mx;
  __syncthreads();
  float gmx = fmaxf(fmaxf(wred[0][ln15], wred[1][ln15]), fmaxf(wred[2][ln15], wred[3][ln15]));
  __syncthreads();
  float s = 0.f;
  #pragma unroll
  for (int p=0; p<4; p++)
    #pragma unroll
    for (int r=0; r<4; r++) s += __expf(tg[p][r] - gmx);
  s += __shfl_xor(s, 16, 64);
  s += __shfl_xor(s, 32, 64);
  wred[wv][ln15] = s;
  __syncthreads();
  float gs = (wred[0][ln15]+wred[1][ln15]) + (wred[2][ln15]+wred[3][ln15]);
  float lz = gmx + __logf(gs);

  #pragma unroll
  for (int p=0; p<4; p++){
    int m = (wv*4+p)*16 + quad*4;
    ushort ob[4];
    #pragma unroll
    for (int r=0; r<4; r++) ob[r] = f2b(tg[p][r] - lz);
    uint2 uu;
    uu.x = (unsigned)ob[0] | ((unsigned)ob[1]<<16);
    uu.y = (unsigned)ob[2] | ((unsigned)ob[3]<<16);
    *(uint2*)&O8B[row*256 + m] = uu;
  }
}

// ---- p8: P8[v] = W_ih @ out8[v] via MFMA ----
__global__ __launch_bounds__(64) void p8_kernel(float* __restrict__ wsf){
  const int nt = blockIdx.x >> 4, eb = blockIdx.x & 15;
  const int lane = threadIdx.x, ln15 = lane & 15, quad = lane >> 4;
  const ushort* FWIH = (const ushort*)(wsf + OFF_FRAG);
  const ushort* O8B  = (const ushort*)(wsf + OFF_O8B);
  const int row = nt*16 + ln15;

  f32x4 acc[4];
  #pragma unroll
  for (int g=0; g<4; g++) acc[g] = (f32x4){0.f,0.f,0.f,0.f};
  #pragma unroll
  for (int ks=0; ks<8; ks++){
    bf16x8 b = *(const bf16x8*)&O8B[row*256 + ks*32 + quad*8];
    #pragma unroll
    for (int g=0; g<4; g++){
      int mt = g*16 + eb;
      bf16x8 a = *(const bf16x8*)&FWIH[((mt*8+ks)<<9) + (lane<<3)];
      acc[g] = __builtin_amdgcn_mfma_f32_16x16x32_bf16(a, b, acc[g], 0,0,0);
    }
  }
  if (row < NVOCAB){
    #pragma unroll
    for (int g=0; g<4; g++)
      *(float4*)&wsf[OFF_P8 + row*1024 + g*256 + eb*16 + quad*4] =
        (float4){acc[g][0], acc[g][1], acc[g][2], acc[g][3]};
  }
}

// ---- t2 table: (h2,c2)[a] = gate(hh1 + P8[a], cp=C1), a<26 ----
__global__ __launch_bounds__(256) void t2tab_kernel(float* __restrict__ wsf){
  int a = blockIdx.x, e = threadIdx.x;
  const float* P8a = wsf + OFF_P8 + (size_t)a*1024;
  float zi = wsf[OFF_HH1+e]     + P8a[e];
  float zf = wsf[OFF_HH1+256+e] + P8a[256+e];
  float zg = wsf[OFF_HH1+512+e] + P8a[512+e];
  float zo = wsf[OFF_HH1+768+e] + P8a[768+e];
  float cn = sigmf(zf)*wsf[OFF_C1+e] + sigmf(zi)*tanhfast(zg);
  ((ushort*)(wsf+OFF_H2B))[a*256+e] = f2b(sigmf(zo)*tanhfast(cn));
  wsf[OFF_C2T + a*256 + e] = cn;
}

// ---- hhmat: Out[r] = bsum + W_hh @ Hrows[r]  (MFMA, eb-sliced) ----
__global__ __launch_bounds__(64) void hhmat_kernel(
    float* __restrict__ wsf, const ushort* __restrict__ Hrows,
    float* __restrict__ Out, int R)
{
  const int nt = blockIdx.x >> 4, eb = blockIdx.x & 15;
  const int lane = threadIdx.x, ln15 = lane & 15, quad = lane >> 4;
  const ushort* FWHH = (const ushort*)(wsf + OFF_FRAG) + 262144;
  int row = nt*16 + ln15;
  int rowc = row < R ? row : R-1;

  f32x4 acc[4];
  #pragma unroll
  for (int g=0; g<4; g++) acc[g] = (f32x4){0.f,0.f,0.f,0.f};
  #pragma unroll
  for (int ks=0; ks<8; ks++){
    bf16x8 b = *(const bf16x8*)&Hrows[rowc*256 + ks*32 + quad*8];
    #pragma unroll
    for (int g=0; g<4; g++){
      int mt = g*16 + eb;
      bf16x8 a = *(const bf16x8*)&FWHH[((mt*8+ks)<<9) + (lane<<3)];
      acc[g] = __builtin_amdgcn_mfma_f32_16x16x32_bf16(a, b, acc[g], 0,0,0);
    }
  }
  if (row < R){
    #pragma unroll
    for (int g=0; g<4; g++){
      int m = g*256 + eb*16 + quad*4;
      float4 bs = *(const float4*)&wsf[OFF_BSUM + m];
      *(float4*)&Out[(size_t)row*1024 + m] =
        (float4){acc[g][0]+bs.x, acc[g][1]+bs.y, acc[g][2]+bs.z, acc[g][3]+bs.w};
    }
  }
}

// ---- t3 table: (h3,c3)[a*26+b] = gate(HH2A[a] + P8[b], cp=C2[a]) ----
__global__ __launch_bounds__(256) void t3tab_kernel(float* __restrict__ wsf){
  int p = blockIdx.x;
  int a = p / 26, b = p - a*26;
  int e = threadIdx.x;
  const float* HA = wsf + OFF_HH2A + (size_t)a*1024;
  const float* PB = wsf + OFF_P8   + (size_t)b*1024;
  float zi = HA[e]     + PB[e];
  float zf = HA[256+e] + PB[256+e];
  float zg = HA[512+e] + PB[512+e];
  float zo = HA[768+e] + PB[768+e];
  float cn = sigmf(zf)*wsf[OFF_C2T + a*256 + e] + sigmf(zi)*tanhfast(zg);
  ((ushort*)(wsf+OFF_H3B))[p*256+e] = f2b(sigmf(zo)*tanhfast(cn));
  wsf[OFF_C3T + p*256 + e] = cn;
}

// ---- l7f: fully fused L7 per-node kernel (full-row blocks of 16 nodes).
// Staging: serial-16, all 256 threads on one node/iter (round-7 proven form). ----
__global__ __launch_bounds__(256) void l7f_kernel(
    const float* __restrict__ wsf, const int* __restrict__ idents,
    ushort* __restrict__ OutNext)
{
  __shared__ __align__(16) ushort HbL[16*STR];   // h4, reused for comb
  __shared__ __align__(16) ushort H5L[16*STR];
  __shared__ float C4L[16*264];
  __shared__ float wred[4][16];
  const int tid=threadIdx.x, wv=tid>>6, lane=tid&63, ln15=lane&15, quad=lane>>4;
  const ushort* FWHH = (const ushort*)(wsf + OFF_FRAG) + 262144;
  const ushort* FWC1 = FWHH + 262144;
  const ushort* FWT  = FWC1 + 65536;
  const float*  EWcP = wsf + OFF_EWC;
  const int nb = blockIdx.x*16;

  #pragma unroll 2
  for (int i=0; i<16; i++){
    const int ib4 = 21845 + (nb+i)*4;
    const int ia = idents[ib4], ibb = idents[ib4+1], icc = idents[ib4+2];
    const int pp = ia*26 + ibb;
    const float* HA = wsf + OFF_HH3 + (size_t)pp*1024;
    const float* PB = wsf + OFF_P8  + (size_t)icc*1024;
    const int e = tid;
    float zi = HA[e]     + PB[e];
    float zf = HA[256+e] + PB[256+e];
    float zg = HA[512+e] + PB[512+e];
    float zo = HA[768+e] + PB[768+e];
    float cn = sigmf(zf)*wsf[OFF_C3T + (size_t)pp*256 + e] + sigmf(zi)*tanhfast(zg);
    C4L[i*264 + e] = cn;
    HbL[i*STR + e] = f2b(sigmf(zo)*tanhfast(cn));
  }
  __syncthreads();

  const int node = nb + ln15;
  const int idd = idents[21845 + node*4 + 3];
  const float* PD = wsf + OFF_P8 + (size_t)idd*1024;

  #pragma unroll 1
  for (int p=0; p<4; p++){
    const int eb = wv*4 + p;
    f32x4 acc[4];
    #pragma unroll
    for (int g=0; g<4; g++) acc[g] = (f32x4){0.f,0.f,0.f,0.f};
    #pragma unroll
    for (int ks=0; ks<8; ks++){
      bf16x8 b = *(const bf16x8*)&HbL[ln15*STR + ks*32 + quad*8];
      #pragma unroll
      for (int g=0; g<4; g++){
        bf16x8 a = *(const bf16x8*)&FWHH[(((g*16+eb)*8+ks)<<9) + (lane<<3)];
        acc[g] = __builtin_amdgcn_mfma_f32_16x16x32_bf16(a, b, acc[g], 0,0,0);
      }
    }
    const int e0 = eb*16 + quad*4;
    float4 bs0 = *(const float4*)&wsf[OFF_BSUM +       e0];
    float4 bs1 = *(const float4*)&wsf[OFF_BSUM + 256 + e0];
    float4 bs2 = *(const float4*)&wsf[OFF_BSUM + 512 + e0];
    float4 bs3 = *(const float4*)&wsf[OFF_BSUM + 768 + e0];
    float4 d0 = *(const float4*)&PD[      e0];
    float4 d1 = *(const float4*)&PD[256 + e0];
    float4 d2 = *(const float4*)&PD[512 + e0];
    float4 d3 = *(const float4*)&PD[768 + e0];
    float4 cp4 = *(const float4*)&C4L[ln15*264 + e0];
    ushort hb[4];
    #pragma unroll
    for (int r=0; r<4; r++){
      float zi = acc[0][r] + ((const float*)&bs0)[r] + ((const float*)&d0)[r];
      float zf = acc[1][r] + ((const float*)&bs1)[r] + ((const float*)&d1)[r];
      float zg = acc[2][r] + ((const float*)&bs2)[r] + ((const float*)&d2)[r];
      float zo = acc[3][r] + ((const float*)&bs3)[r] + ((const float*)&d3)[r];
      float cn = sigmf(zf)*((const float*)&cp4)[r] + sigmf(zi)*tanhfast(zg);
      hb[r] = f2b(sigmf(zo)*tanhfast(cn));
    }
    uint2 uu;
    uu.x = (unsigned)hb[0] | ((unsigned)hb[1]<<16);
    uu.y = (unsigned)hb[2] | ((unsigned)hb[3]<<16);
    *(uint2*)&H5L[ln15*STR + e0] = uu;
  }
  __syncthreads();

  const int myid = idents[5461 + node];
  #pragma unroll 1
  for (int p=0; p<4; p++){
    const int mt = wv*4 + p;
    f32x4 ac = (f32x4){0.f,0.f,0.f,0.f};
    #pragma unroll
    for (int ks=0; ks<8; ks++){
      bf16x8 a = *(const bf16x8*)&FWC1[((mt*8+ks)<<9) + (lane<<3)];
      bf16x8 b = *(const bf16x8*)&H5L[ln15*STR + ks*32 + quad*8];
      ac = __builtin_amdgcn_mfma_f32_16x16x32_bf16(a, b, ac, 0,0,0);
    }
    float4 ew = *(const float4*)&EWcP[(size_t)myid*256 + mt*16 + quad*4];
    ushort cb[4];
    #pragma unroll
    for (int r=0; r<4; r++) cb[r] = f2b(ac[r] + ((const float*)&ew)[r]);
    uint2 uu;
    uu.x = (unsigned)cb[0] | ((unsigned)cb[1]<<16);
    uu.y = (unsigned)cb[2] | ((unsigned)cb[3]<<16);
    *(uint2*)&HbL[ln15*STR + mt*16 + quad*4] = uu;
  }
  __syncthreads();

  f32x4 tg[4];
  #pragma unroll 1
  for (int p=0; p<4; p++){
    const int mt = wv*4 + p;
    tg[p] = (f32x4){0.f,0.f,0.f,0.f};
    #pragma unroll
    for (int ks=0; ks<8; ks++){
      bf16x8 a = *(const bf16x8*)&FWT[((mt*8+ks)<<9) + (lane<<3)];
      bf16x8 b = *(const bf16x8*)&HbL[ln15*STR + ks*32 + quad*8];
      tg[p] = __builtin_amdgcn_mfma_f32_16x16x32_bf16(a, b, tg[p], 0,0,0);
    }
    float4 bt4 = *(const float4*)&wsf[OFF_BTF + mt*16 + quad*4];
    #pragma unroll
    for (int r=0; r<4; r++) tg[p][r] += ((const float*)&bt4)[r];
  }

  float mx = -3.0e38f;
  #pragma unroll
  for (int p=0; p<4; p++)
    #pragma unroll
    for (int r=0; r<4; r++) mx = fmaxf(mx, tg[p][r]);
  mx = fmaxf(mx, __shfl_xor(mx, 16, 64));
  mx = fmaxf(mx, __shfl_xor(mx, 32, 64));
  wred[wv][ln15] = mx;
  __syncthreads();
  float gmx = fmaxf(fmaxf(wred[0][ln15], wred[1][ln15]), fmaxf(wred[2][ln15], wred[3][ln15]));
  __syncthreads();
  float s = 0.f;
  #pragma unroll
  for (int p=0; p<4; p++)
    #pragma unroll
    for (int r=0; r<4; r++) s += __expf(tg[p][r] - gmx);
  s += __shfl_xor(s, 16, 64);
  s += __shfl_xor(s, 32, 64);
  wred[wv][ln15] = s;
  __syncthreads();
  float gs = (wred[0][ln15]+wred[1][ln15]) + (wred[2][ln15]+wred[3][ln15]);
  float lz = gmx + __logf(gs);

  #pragma unroll
  for (int p=0; p<4; p++){
    int m = (wv*4+p)*16 + quad*4;
    ushort ob[4];
    #pragma unroll
    for (int r=0; r<4; r++) ob[r] = f2b(tg[p][r] - lz);
    uint2 uu;
    uu.x = (unsigned)ob[0] | ((unsigned)ob[1]<<16);
    uu.y = (unsigned)ob[2] | ((unsigned)ob[3]<<16);
    *(uint2*)&OutNext[(size_t)node*256 + m] = uu;
  }
}

// ---- one LSTM t-step: eb-sliced, 64 thr (proven shape, VGPR ~52).
// SWZ=true (requires nTiles%8==0): all 16 eb-blocks of a node tile share
// bid%8 -> same XCD L2 (B rows fetched once, output lines merged). ----
template<bool FIRST, bool SWZ>
__global__ __launch_bounds__(64) void step_kernel(
    const float* __restrict__ wsf, const ushort* __restrict__ OutPrev,
    const ushort* __restrict__ Hin, ushort* __restrict__ Hout,
    float* __restrict__ Cbuf, int nNodes, int tm1)
{
  const int bid = blockIdx.x;
  int nt, eb;
  if (SWZ){
    const int xcd = bid & 7;
    const int j   = bid >> 3;
    eb = j & 15;
    nt = (j >> 4)*8 + xcd;
  } else {
    nt = bid >> 4;
    eb = bid & 15;
  }
  const int lane = threadIdx.x;
  const int ln15 = lane & 15;
  const int quad = lane >> 4;

  const ushort* FWIH = (const ushort*)(wsf + OFF_FRAG);
  const ushort* FWHH = FWIH + 262144;

  int node = nt*16 + ln15; if (node >= nNodes) node = nNodes-1;
  const int rowX = (node*4 + tm1) * 256;
  const int rowH = node * 256;

  f32x4 acc[4];
  #pragma unroll
  for (int g=0; g<4; g++) acc[g] = (f32x4){0.f,0.f,0.f,0.f};

  #pragma unroll
  for (int ks=0; ks<8; ks++){
    bf16x8 bx = *(const bf16x8*)&OutPrev[rowX + ks*32 + quad*8];
    bf16x8 bh;
    if (!FIRST) bh = *(const bf16x8*)&Hin[rowH + ks*32 + quad*8];
    #pragma unroll
    for (int g=0; g<4; g++){
      int mt = g*16 + eb;
      bf16x8 a = *(const bf16x8*)&FWIH[((mt*8+ks)<<9) + (lane<<3)];
      acc[g] = __builtin_amdgcn_mfma_f32_16x16x32_bf16(a, bx, acc[g], 0,0,0);
      if (!FIRST){
        bf16x8 a2 = *(const bf16x8*)&FWHH[((mt*8+ks)<<9) + (lane<<3)];
        acc[g] = __builtin_amdgcn_mfma_f32_16x16x32_bf16(a2, bh, acc[g], 0,0,0);
      }
    }
  }

  const float* baseP = wsf + (FIRST ? OFF_HH1 : OFF_BSUM);
  const int e0 = eb*16 + quad*4;
  float4 b0 = *(const float4*)&baseP[       e0];
  float4 b1 = *(const float4*)&baseP[ 256 + e0];
  float4 b2 = *(const float4*)&baseP[ 512 + e0];
  float4 b3 = *(const float4*)&baseP[ 768 + e0];
  float4 cp;
  if (FIRST) cp = *(const float4*)&wsf[OFF_C1 + e0];
  else       cp = *(const float4*)&Cbuf[rowH + e0];

  float cn4[4]; ushort hb[4];
  #pragma unroll
  for (int r=0; r<4; r++){
    float zi = acc[0][r] + ((const float*)&b0)[r];
    float zf = acc[1][r] + ((const float*)&b1)[r];
    float zg = acc[2][r] + ((const float*)&b2)[r];
    float zo = acc[3][r] + ((const float*)&b3)[r];
    float cn = sigmf(zf)*((const float*)&cp)[r] + sigmf(zi)*tanhfast(zg);
    cn4[r] = cn;
    hb[r] = f2b(sigmf(zo)*tanhfast(cn));
  }
  *(float4*)&Cbuf[rowH + e0] = (float4){cn4[0],cn4[1],cn4[2],cn4[3]};
  uint2 uu;
  uu.x = (unsigned)hb[0] | ((unsigned)hb[1]<<16);
  uu.y = (unsigned)hb[2] | ((unsigned)hb[3]<<16);
  *(uint2*)&Hout[rowH + e0] = uu;
}

// ---- step4: 4 LSTM steps in ONE cooperative launch (tail levels, n<=256).
// Blocks are the PROVEN eb-sliced 64-thread shape; grid.sync() between steps
// replaces 3 launch boundaries. Memory behavior identical to step_kernel. ----
__global__ __launch_bounds__(64) void step4_kernel(
    const float* __restrict__ wsf, const ushort* __restrict__ OutPrev,
    ushort* __restrict__ HbA, ushort* __restrict__ HbB,
    float* __restrict__ Cbuf, int nNodes)
{
  cg::grid_group grid = cg::this_grid();
  const int nt = blockIdx.x >> 4;
  const int eb = blockIdx.x & 15;
  const int lane = threadIdx.x;
  const int ln15 = lane & 15;
  const int quad = lane >> 4;

  const ushort* FWIH = (const ushort*)(wsf + OFF_FRAG);
  const ushort* FWHH = FWIH + 262144;

  int node = nt*16 + ln15; if (node >= nNodes) node = nNodes-1;
  const int rowH = node * 256;
  const int e0 = eb*16 + quad*4;

  #pragma unroll 1
  for (int t=0; t<4; t++){
    const ushort* Hin  = (t==2) ? HbB : HbA;        // t1,t3 read HbA; t2 reads HbB
    ushort* Hout       = (t==0||t==2) ? HbA : HbB;  // t0,t2 write HbA; t1,t3 write HbB
    const int rowX = (node*4 + t) * 256;

    f32x4 acc[4];
    #pragma unroll
    for (int g=0; g<4; g++) acc[g] = (f32x4){0.f,0.f,0.f,0.f};

    #pragma unroll
    for (int ks=0; ks<8; ks++){
      bf16x8 bx = *(const bf16x8*)&OutPrev[rowX + ks*32 + quad*8];
      bf16x8 bh;
      if (t > 0) bh = *(const bf16x8*)&Hin[rowH + ks*32 + quad*8];
      #pragma unroll
      for (int g=0; g<4; g++){
        int mt = g*16 + eb;
        bf16x8 a = *(const bf16x8*)&FWIH[((mt*8+ks)<<9) + (lane<<3)];
        acc[g] = __builtin_amdgcn_mfma_f32_16x16x32_bf16(a, bx, acc[g], 0,0,0);
        if (t > 0){
          bf16x8 a2 = *(const bf16x8*)&FWHH[((mt*8+ks)<<9) + (lane<<3)];
          acc[g] = __builtin_amdgcn_mfma_f32_16x16x32_bf16(a2, bh, acc[g], 0,0,0);
        }
      }
    }

    const float* baseP = wsf + (t==0 ? OFF_HH1 : OFF_BSUM);
    float4 b0 = *(const float4*)&baseP[       e0];
    float4 b1 = *(const float4*)&baseP[ 256 + e0];
    float4 b2 = *(const float4*)&baseP[ 512 + e0];
    float4 b3 = *(const float4*)&baseP[ 768 + e0];
    float4 cp;
    if (t==0) cp = *(const float4*)&wsf[OFF_C1 + e0];
    else      cp = *(const float4*)&Cbuf[rowH + e0];

    float cn4[4]; ushort hb[4];
    #pragma unroll
    for (int r=0; r<4; r++){
      float zi = acc[0][r] + ((const float*)&b0)[r];
      float zf = acc[1][r] + ((const float*)&b1)[r];
      float zg = acc[2][r] + ((const float*)&b2)[r];
      float zo = acc[3][r] + ((const float*)&b3)[r];
      float cn = sigmf(zf)*((const float*)&cp)[r] + sigmf(zi)*tanhfast(zg);
      cn4[r] = cn;
      hb[r] = f2b(sigmf(zo)*tanhfast(cn));
    }
    *(float4*)&Cbuf[rowH + e0] = (float4){cn4[0],cn4[1],cn4[2],cn4[3]};
    uint2 uu;
    uu.x = (unsigned)hb[0] | ((unsigned)hb[1]<<16);
    uu.y = (unsigned)hb[2] | ((unsigned)hb[3]<<16);
    *(uint2*)&Hout[rowH + e0] = uu;

    if (t < 3){
      __threadfence();
      grid.sync();
    }
  }
}

// ---- epilogue for step levels: combine -> tag -> log-softmax -> out ----
template<bool FINAL>
__global__ __launch_bounds__(256) void fin_kernel(
    const float* __restrict__ wsf, const ushort* __restrict__ Hfin,
    const int* __restrict__ idents, int offL, int nNodes,
    ushort* __restrict__ OutNext, void* __restrict__ dout)
{
  __shared__ __align__(16) ushort Clds[16*STR];
  __shared__ float wred[4][16];
  const int tid  = threadIdx.x;
  const int wv   = tid >> 6;
  const int lane = tid & 63;
  const int ln15 = lane & 15;
  const int quad = lane >> 4;
  const int nt   = blockIdx.x;

  const ushort* FWIH = (const ushort*)(wsf + OFF_FRAG);
  const ushort* FWC1 = FWIH + 262144 + 262144;
  const ushort* FWT  = FWC1 + 65536;
  const float*  EWcP = wsf + OFF_EWC;

  int node = nt*16 + ln15; if (node >= nNodes) node = nNodes-1;
  const int myid = idents[offL + node];
  const int rowH = node * 256;

  #pragma unroll 1
  for (int p=0; p<4; p++){
    const int mt = wv*4 + p;
    f32x4 ac = (f32x4){0.f,0.f,0.f,0.f};
    #pragma unroll
    for (int ks=0; ks<8; ks++){
      bf16x8 a = *(const bf16x8*)&FWC1[((mt*8+ks)<<9) + (lane<<3)];
      bf16x8 b = *(const bf16x8*)&Hfin[rowH + ks*32 + quad*8];
      ac = __builtin_amdgcn_mfma_f32_16x16x32_bf16(a, b, ac, 0,0,0);
    }
    float4 ew = *(const float4*)&EWcP[(size_t)myid*256 + mt*16 + quad*4];
    ushort cb[4];
    #pragma unroll
    for (int r=0; r<4; r++) cb[r] = f2b(ac[r] + ((const float*)&ew)[r]);
    uint2 uu;
    uu.x = (unsigned)cb[0] | ((unsigned)cb[1]<<16);
    uu.y = (unsigned)cb[2] | ((unsigned)cb[3]<<16);
    *(uint2*)&Clds[ln15*STR + mt*16 + quad*4] = uu;
  }
  __syncthreads();

  f32x4 tg[4];
  #pragma unroll 1
  for (int p=0; p<4; p++){
    const int mt = wv*4 + p;
    tg[p] = (f32x4){0.f,0.f,0.f,0.f};
    #pragma unroll
    for (int ks=0; ks<8; ks++){
      bf16x8 a = *(const bf16x8*)&FWT[((mt*8+ks)<<9) + (lane<<3)];
      bf16x8 b = *(const bf16x8*)&Clds[ln15*STR + ks*32 + quad*8];
      tg[p] = __builtin_amdgcn_mfma_f32_16x16x32_bf16(a, b, tg[p], 0,0,0);
    }
    float4 bt4 = *(const float4*)&wsf[OFF_BTF + mt*16 + quad*4];
    #pragma unroll
    for (int r=0; r<4; r++) tg[p][r] += ((const float*)&bt4)[r];
  }

  float mx = -3.0e38f;
  #pragma unroll
  for (int p=0; p<4; p++)
    #pragma unroll
    for (int r=0; r<4; r++) mx = fmaxf(mx, tg[p][r]);
  mx = fmaxf(mx, __shfl_xor(mx, 16, 64));
  mx = fmaxf(mx, __shfl_xor(mx, 32, 64));
  wred[wv][ln15] = mx;
  __syncthreads();
  float gmx = fmaxf(fmaxf(wred[0][ln15], wred[1][ln15]), fmaxf(wred[2][ln15], wred[3][ln15]));
  __syncthreads();
  float s = 0.f;
  #pragma unroll
  for (int p=0; p<4; p++)
    #pragma unroll
    for (int r=0; r<4; r++) s += __expf(tg[p][r] - gmx);
  s += __shfl_xor(s, 16, 64);
  s += __shfl_xor(s, 32, 64);
  wred[wv][ln15] = s;
  __syncthreads();
  float gs = (wred[0][ln15]+wred[1][ln15]) + (wred[2][ln15]+wred[3][ln15]);
  float lz = gmx + __logf(gs);

  if (FINAL){
    if (ln15 == 0){
      const int f32o = ((const int*)wsf)[1] != 0;
      #pragma unroll
      for (int p=0; p<4; p++){
        #pragma unroll
        for (int r=0; r<4; r++){
          int m = (wv*4+p)*16 + quad*4 + r;
          float v = tg[p][r] - lz;
          if (f32o) ((float*)dout)[m] = v;
          else      ((ushort*)dout)[m] = f2b(v);
        }
      }
    }
    return;
  }
  int onode = nt*16 + ln15;
  if (onode < nNodes){
    #pragma unroll
    for (int p=0; p<4; p++){
      int m = (wv*4+p)*16 + quad*4;
      ushort ob[4];
      #pragma unroll
      for (int r=0; r<4; r++) ob[r] = f2b(tg[p][r] - lz);
      uint2 uu;
      uu.x = (unsigned)ob[0] | ((unsigned)ob[1]<<16);
      uu.y = (unsigned)ob[2] | ((unsigned)ob[3]<<16);
      *(uint2*)&OutNext[(size_t)onode*256 + m] = uu;
    }
  }
}

extern "C" void kernel_launch(void* const* d_in, const int* in_sizes, int n_in,
                              void* d_out, int out_size, void* d_ws, size_t ws_size,
                              hipStream_t stream)
{
  (void)in_sizes; (void)n_in; (void)out_size; (void)ws_size;
  const int* idents = (const int*)d_in[0];
  const void* emb   = d_in[1];
  const void* W_ih  = d_in[2];
  const void* W_hh  = d_in[3];
  const void* b_ih  = d_in[4];
  const void* b_hh  = d_in[5];
  const void* Wc    = d_in[6];
  const void* bc    = d_in[7];
  const void* Wt    = d_in[8];
  const void* bt    = d_in[9];
  const void* linit = d_in[10];

  float* wsf = (float*)d_ws;
  ushort* slabA = (ushort*)(wsf + OFF_SLABS);
  ushort* slabB = slabA + (size_t)16384*256;
  ushort* Hb0   = slabB + (size_t)4096*256;      // 4096 rows (L6-sized)
  ushort* Hb1   = Hb0 + (size_t)4096*256;
  float*  Cb    = (float*)(Hb1 + (size_t)4096*256);

  init_kernel  <<<1, 64, 0, stream>>>((int*)d_ws);
  detect_kernel<<<16, 256, 0, stream>>>((int*)d_ws, (const uint4*)W_ih);
  zpe_kernel   <<<158, 256, 0, stream>>>(wsf, W_ih, b_ih, b_hh, bt, linit, W_hh, Wc, Wt, emb, bc);
  hh1x_kernel  <<<5, 256, 0, stream>>>(wsf, W_hh, Wc);
  tag8_kernel  <<<2, 256, 0, stream>>>(wsf);
  p8_kernel    <<<32, 64, 0, stream>>>(wsf);

  // L7 child-prefix tables (parallel, proven)
  t2tab_kernel <<<NVOCAB, 256, 0, stream>>>(wsf);
  hhmat_kernel <<<32, 64, 0, stream>>>(wsf, (const ushort*)(wsf+OFF_H2B), wsf+OFF_HH2A, NVOCAB);
  t3tab_kernel <<<NVOCAB*NVOCAB, 256, 0, stream>>>(wsf);
  hhmat_kernel <<<((NVOCAB*NVOCAB+15)/16)*16, 64, 0, stream>>>(wsf, (const ushort*)(wsf+OFF_H3B), wsf+OFF_HH3, NVOCAB*NVOCAB);

  // L7: single fused kernel (h4 -> t5 -> combine -> tag -> softmax)
  l7f_kernel   <<<1024, 256, 0, stream>>>(wsf, idents, slabA);

  // L6 (4096) and L5 (1024): eb-sliced steps with XCD swizzle + fin
  step_kernel<true ,true><<<4096, 64, 0, stream>>>(wsf, slabA, nullptr, Hb1, Cb, 4096, 0);
  step_kernel<false,true><<<4096, 64, 0, stream>>>(wsf, slabA, Hb1, Hb0, Cb, 4096, 1);
  step_kernel<false,true><<<4096, 64, 0, stream>>>(wsf, slabA, Hb0, Hb1, Cb, 4096, 2);
  step_kernel<false,true><<<4096, 64, 0, stream>>>(wsf, slabA, Hb1, Hb0, Cb, 4096, 3);
  fin_kernel<false><<<256, 256, 0, stream>>>(wsf, Hb0, idents, 1365, 4096, slabB, nullptr);
  step_kernel<true ,true><<<1024, 64, 0, stream>>>(wsf, slabB, nullptr, Hb1, Cb, 1024, 0);
  step_kernel<false,true><<<1024, 64, 0, stream>>>(wsf, slabB, Hb1, Hb0, Cb, 1024, 1);
  step_kernel<false,true><<<1024, 64, 0, stream>>>(wsf, slabB, Hb0, Hb1, Cb, 1024, 2);
  step_kernel<false,true><<<1024, 64, 0, stream>>>(wsf, slabB, Hb1, Hb0, Cb, 1024, 3);
  fin_kernel<false><<<64, 256, 0, stream>>>(wsf, Hb0, idents, 341, 1024, slabA, nullptr);

  // L4..L0: one cooperative step4 (4 steps, eb-sliced blocks, grid.sync) + fin
  // per level. Final h lands in Hb0 (t3 writes HbB).
  struct Lv { int n, offL; ushort *P, *O; };
  const Lv lv[5] = {
    {256,  85, slabA, slabB},
    { 64,  21, slabB, slabA},
    { 16,   5, slabA, slabB},
    {  4,   1, slabB, slabA},
    {  1,   0, slabA, nullptr},
  };
  for (int i=0; i<5; i++){
    int nt = (lv[i].n + 15) / 16;
    const float* wsfc = wsf;
    const ushort* prev = lv[i].P;
    ushort* hbA = Hb1;
    ushort* hbB = Hb0;
    float* cb = Cb;
    int nn = lv[i].n;
    void* args[6] = { (void*)&wsfc, (void*)&prev, (void*)&hbA, (void*)&hbB, (void*)&cb, (void*)&nn };
    hipLaunchCooperativeKernel((void*)step4_kernel, dim3(nt*16), dim3(64), args, 0, stream);
    if (i < 4) fin_kernel<false><<<nt, 256, 0, stream>>>(wsf, Hb0, idents, lv[i].offL, lv[i].n, lv[i].O, nullptr);
    else       fin_kernel<true ><<<1,  256, 0, stream>>>(wsf, Hb0, idents, 0, 1, nullptr, d_out);
  }
}

// Round 11
// 456.720 us; speedup vs baseline: 2.1314x; 1.8272x over previous
//
#include <hip/hip_runtime.h>
#include <hip/hip_bf16.h>
#include <cstdint>
#include <cstddef>

typedef __hip_bfloat16 bf16;
typedef unsigned short ushort;
typedef __attribute__((ext_vector_type(8))) short bf16x8;
typedef __attribute__((ext_vector_type(4))) float f32x4;

#define HDIM 256
#define NVOCAB 26
#define STR 264

// ---- workspace layout (float offsets) ----
#define OFF_BSUM  16
#define OFF_Z1    (OFF_BSUM+1024)
#define OFF_HH1   (OFF_Z1+1024)
#define OFF_H1    (OFF_HH1+1024)
#define OFF_C1    (OFF_H1+256)
#define OFF_WCH1  (OFF_C1+256)
#define OFF_BTF   (OFF_WCH1+256)
#define OFF_EWC   (OFF_BTF+256)          // [26][256] f32
#define OFF_P8    (OFF_EWC+6656)         // [26][1024] f32
#define OFF_SCB   (OFF_P8+26624)         // [32][256] ushort (scomb bf16)
#define OFF_O8B   (OFF_SCB+4096)         // [32][256] ushort (out8 bf16)
#define OFF_H2B   (OFF_O8B+4096)         // [32][256] ushort (h2 per child0-id)
#define OFF_C2T   (OFF_H2B+4096)         // [32][256] f32
#define OFF_HH2A  (OFF_C2T+8192)         // [32][1024] f32 (bsum + W_hh@h2)
#define OFF_H3B   (OFF_HH2A+32768)       // [704][256] ushort (h3 per (id0,id1))
#define OFF_C3T   (OFF_H3B+90112)        // [704][256] f32
#define OFF_HH3   (OFF_C3T+180224)       // [704][1024] f32 (bsum + W_hh@h3)
#define OFF_FRAG  (OFF_HH3+720896)       // ushort frag tables
#define OFF_SLABS (OFF_FRAG+327680)

__device__ __forceinline__ float sigmf(float x){ return 1.0f/(1.0f+__expf(-x)); }
__device__ __forceinline__ float tanhfast(float x){ return 1.0f - 2.0f/(__expf(2.0f*x)+1.0f); }
__device__ __forceinline__ ushort f2b(float x){ bf16 h = __float2bfloat16(x); return *(ushort*)&h; }
__device__ __forceinline__ float ldin(const void* p, int i, int f32){
  if (f32) return ((const float*)p)[i];
  unsigned int w = ((unsigned int)((const ushort*)p)[i]) << 16;
  return __uint_as_float(w);
}
__device__ __forceinline__ void ld8(const void* p, int i, int f32, float* o){
  if (f32){
    float4 a = *(const float4*)((const float*)p + i);
    float4 b = *(const float4*)((const float*)p + i + 4);
    o[0]=a.x;o[1]=a.y;o[2]=a.z;o[3]=a.w;o[4]=b.x;o[5]=b.y;o[6]=b.z;o[7]=b.w;
  } else {
    uint4 u = *(const uint4*)((const ushort*)p + i);
    unsigned w0=u.x,w1=u.y,w2=u.z,w3=u.w;
    o[0]=__uint_as_float(w0<<16); o[1]=__uint_as_float(w0&0xFFFF0000u);
    o[2]=__uint_as_float(w1<<16); o[3]=__uint_as_float(w1&0xFFFF0000u);
    o[4]=__uint_as_float(w2<<16); o[5]=__uint_as_float(w2&0xFFFF0000u);
    o[6]=__uint_as_float(w3<<16); o[7]=__uint_as_float(w3&0xFFFF0000u);
  }
}
__device__ __forceinline__ uint4 pack8(const ushort* h){
  uint4 u;
  u.x = (unsigned)h[0] | ((unsigned)h[1]<<16);
  u.y = (unsigned)h[2] | ((unsigned)h[3]<<16);
  u.z = (unsigned)h[4] | ((unsigned)h[5]<<16);
  u.w = (unsigned)h[6] | ((unsigned)h[7]<<16);
  return u;
}

__global__ void init_kernel(int* wsI){ if (threadIdx.x<4) wsI[threadIdx.x]=0; }

__global__ __launch_bounds__(256) void detect_kernel(int* wsI, const uint4* wih4){
  int c=0;
  for (int i = blockIdx.x*blockDim.x + threadIdx.x; i < 32768; i += gridDim.x*blockDim.x){
    uint4 u = wih4[i];
    unsigned w[4] = {u.x,u.y,u.z,u.w};
    #pragma unroll
    for (int j=0;j<4;j++){
      if ((w[j] & 0x7F80u) == 0x7F80u) c++;
      if ((w[j] & 0x7F800000u) == 0x7F800000u) c++;
    }
  }
  #pragma unroll
  for (int o=32;o>0;o>>=1) c += __shfl_xor(c,o,64);
  if ((threadIdx.x&63)==0 && c) atomicAdd(&wsI[1], c);
}

// ---- zpe: fused z1 (blocks 0..3) + prep (4..131) + ewc (132..157) ----
__global__ __launch_bounds__(256) void zpe_kernel(
    float* __restrict__ wsf, const void* W_ih, const void* b_ih, const void* b_hh,
    const void* bt, const void* linit, const void* W_hh, const void* Wc,
    const void* Wt, const void* emb, const void* bc)
{
  const int f32 = ((const int*)wsf)[1] != 0;
  const int bid = blockIdx.x;
  const int tid = threadIdx.x;

  if (bid < 4){
    __shared__ float sx[256];
    int r = bid*256 + tid;
    sx[tid] = ldin(linit, tid, f32);
    __syncthreads();
    float a = ldin(b_ih, r, f32) + ldin(b_hh, r, f32);
    wsf[OFF_BSUM + r] = a;
    float z = a;
    #pragma unroll 8
    for (int k=0;k<256;k+=8){
      float w[8]; ld8(W_ih, r*256+k, f32, w);
      #pragma unroll
      for (int j=0;j<8;j++) z += w[j]*sx[k+j];
    }
    wsf[OFF_Z1 + r] = z;
    if (bid==0) wsf[OFF_BTF + tid] = ldin(bt, tid, f32);
  } else if (bid < 132){
    ushort* FWIH = (ushort*)(wsf + OFF_FRAG);
    ushort* FWHH = FWIH + 262144;
    ushort* FWC1 = FWHH + 262144;
    ushort* FWT  = FWC1 + 65536;
    int t0 = (bid-4)*256 + tid;   // 0..32767
    {
      int i = t0;
      int c = i >> 6, L = i & 63;
      int mt = c>>3, ks = c&7;
      int m = (mt<<4) | (L&15);
      int k0 = (ks<<5) + ((L>>4)<<3);
      float w[8]; ushort h[8];
      ld8(W_ih, m*256+k0, f32, w);
      #pragma unroll
      for (int j=0;j<8;j++) h[j]=f2b(w[j]);
      *(uint4*)&FWIH[(c<<9)+(L<<3)] = pack8(h);
      ld8(W_hh, m*256+k0, f32, w);
      #pragma unroll
      for (int j=0;j<8;j++) h[j]=f2b(w[j]);
      *(uint4*)&FWHH[(c<<9)+(L<<3)] = pack8(h);
    }
    if (t0 < 8192){
      int i = t0;
      int c = i >> 6, L = i & 63;
      int mt = c>>3, ks = c&7;
      int m = (mt<<4) | (L&15);
      int k0 = (ks<<5) + ((L>>4)<<3);
      float w[8]; ushort h[8];
      ld8(Wc, m*512+k0, f32, w);
      #pragma unroll
      for (int j=0;j<8;j++) h[j]=f2b(w[j]);
      *(uint4*)&FWC1[(c<<9)+(L<<3)] = pack8(h);
      ld8(Wt, m*256+k0, f32, w);
      #pragma unroll
      for (int j=0;j<8;j++) h[j]=f2b(w[j]);
      *(uint4*)&FWT[(c<<9)+(L<<3)] = pack8(h);
    }
  } else {
    __shared__ float se[256];
    int v = bid - 132, i = tid;
    se[i] = ldin(emb, v*256+i, f32);
    __syncthreads();
    float a = ldin(bc, i, f32);
    #pragma unroll 8
    for (int k=0;k<256;k+=8){
      float w[8]; ld8(Wc, i*512+256+k, f32, w);
      #pragma unroll
      for (int j=0;j<8;j++) a += w[j]*se[k+j];
    }
    wsf[OFF_EWC + v*256 + i] = a;
  }
}

// ---- hh1x: derives h1 from Z1 in-block (h1 folded in) ----
__global__ __launch_bounds__(256) void hh1x_kernel(float* __restrict__ wsf, const void* W_hh, const void* Wc){
  const int f32 = ((const int*)wsf)[1] != 0;
  __shared__ float sh1[256];
  int tid = threadIdx.x;
  float zi0 = wsf[OFF_Z1+tid], zg0 = wsf[OFF_Z1+512+tid], zo0 = wsf[OFF_Z1+768+tid];
  float c1 = sigmf(zi0)*tanhfast(zg0);
  float h1 = sigmf(zo0)*tanhfast(c1);
  sh1[tid] = h1;
  __syncthreads();
  if (blockIdx.x < 4){
    int r = blockIdx.x*256 + tid;
    float z = wsf[OFF_BSUM + r];
    #pragma unroll 8
    for (int k=0;k<256;k+=8){
      float w[8]; ld8(W_hh, r*256+k, f32, w);
      #pragma unroll
      for (int j=0;j<8;j++) z += w[j]*sh1[k+j];
    }
    wsf[OFF_HH1 + r] = z;
  } else {
    wsf[OFF_H1 + tid] = h1;
    wsf[OFF_C1 + tid] = c1;
    float a = 0.f;
    #pragma unroll 8
    for (int k=0;k<256;k+=8){
      float w[8]; ld8(Wc, tid*512+k, f32, w);
      #pragma unroll
      for (int j=0;j<8;j++) a += w[j]*sh1[k+j];
    }
    wsf[OFF_WCH1 + tid] = a;
    ushort* SCB = (ushort*)(wsf + OFF_SCB);
    #pragma unroll 1
    for (int v32=0; v32<32; v32++){
      int v = v32 < NVOCAB ? v32 : NVOCAB-1;
      SCB[v32*256 + tid] = f2b(a + wsf[OFF_EWC + v*256 + tid]);
    }
  }
}

// ---- tag8: tag = Wt@scomb + bt, log-softmax, out8 bf16 rows (26 vocab) ----
__global__ __launch_bounds__(256) void tag8_kernel(float* __restrict__ wsf){
  __shared__ float wred[4][16];
  const int tid=threadIdx.x, wv=tid>>6, lane=tid&63, ln15=lane&15, quad=lane>>4;
  const int nt = blockIdx.x;
  const ushort* FWT = (const ushort*)(wsf + OFF_FRAG) + 262144 + 262144 + 65536;
  const ushort* SCB = (const ushort*)(wsf + OFF_SCB);
  ushort* O8B = (ushort*)(wsf + OFF_O8B);
  const int row = nt*16 + ln15;

  f32x4 tg[4];
  #pragma unroll 1
  for (int p=0; p<4; p++){
    const int mt = wv*4 + p;
    tg[p] = (f32x4){0.f,0.f,0.f,0.f};
    #pragma unroll
    for (int ks=0; ks<8; ks++){
      bf16x8 a = *(const bf16x8*)&FWT[((mt*8+ks)<<9) + (lane<<3)];
      bf16x8 b = *(const bf16x8*)&SCB[row*256 + ks*32 + quad*8];
      tg[p] = __builtin_amdgcn_mfma_f32_16x16x32_bf16(a, b, tg[p], 0,0,0);
    }
    float4 bt4 = *(const float4*)&wsf[OFF_BTF + mt*16 + quad*4];
    #pragma unroll
    for (int r=0; r<4; r++) tg[p][r] += ((const float*)&bt4)[r];
  }

  float mx = -3.0e38f;
  #pragma unroll
  for (int p=0; p<4; p++)
    #pragma unroll
    for (int r=0; r<4; r++) mx = fmaxf(mx, tg[p][r]);
  mx = fmaxf(mx, __shfl_xor(mx, 16, 64));
  mx = fmaxf(mx, __shfl_xor(mx, 32, 64));
  wred[wv][ln15] = mx;
  __syncthreads();
  float gmx = fmaxf(fmaxf(wred[0][ln15], wred[1][ln15]), fmaxf(wred[2][ln15], wred[3][ln15]));
  __syncthreads();
  float s = 0.f;
  #pragma unroll
  for (int p=0; p<4; p++)
    #pragma unroll
    for (int r=0; r<4; r++) s += __expf(tg[p][r] - gmx);
  s += __shfl_xor(s, 16, 64);
  s += __shfl_xor(s, 32, 64);
  wred[wv][ln15] = s;
  __syncthreads();
  float gs = (wred[0][ln15]+wred[1][ln15]) + (wred[2][ln15]+wred[3][ln15]);
  float lz = gmx + __logf(gs);

  #pragma unroll
  for (int p=0; p<4; p++){
    int m = (wv*4+p)*16 + quad*4;
    ushort ob[4];
    #pragma unroll
    for (int r=0; r<4; r++) ob[r] = f2b(tg[p][r] - lz);
    uint2 uu;
    uu.x = (unsigned)ob[0] | ((unsigned)ob[1]<<16);
    uu.y = (unsigned)ob[2] | ((unsigned)ob[3]<<16);
    *(uint2*)&O8B[row*256 + m] = uu;
  }
}

// ---- p8: P8[v] = W_ih @ out8[v] via MFMA ----
__global__ __launch_bounds__(64) void p8_kernel(float* __restrict__ wsf){
  const int nt = blockIdx.x >> 4, eb = blockIdx.x & 15;
  const int lane = threadIdx.x, ln15 = lane & 15, quad = lane >> 4;
  const ushort* FWIH = (const ushort*)(wsf + OFF_FRAG);
  const ushort* O8B  = (const ushort*)(wsf + OFF_O8B);
  const int row = nt*16 + ln15;

  f32x4 acc[4];
  #pragma unroll
  for (int g=0; g<4; g++) acc[g] = (f32x4){0.f,0.f,0.f,0.f};
  #pragma unroll
  for (int ks=0; ks<8; ks++){
    bf16x8 b = *(const bf16x8*)&O8B[row*256 + ks*32 + quad*8];
    #pragma unroll
    for (int g=0; g<4; g++){
      int mt = g*16 + eb;
      bf16x8 a = *(const bf16x8*)&FWIH[((mt*8+ks)<<9) + (lane<<3)];
      acc[g] = __builtin_amdgcn_mfma_f32_16x16x32_bf16(a, b, acc[g], 0,0,0);
    }
  }
  if (row < NVOCAB){
    #pragma unroll
    for (int g=0; g<4; g++)
      *(float4*)&wsf[OFF_P8 + row*1024 + g*256 + eb*16 + quad*4] =
        (float4){acc[g][0], acc[g][1], acc[g][2], acc[g][3]};
  }
}

// ---- t2 table: (h2,c2)[a] = gate(hh1 + P8[a], cp=C1), a<26 ----
__global__ __launch_bounds__(256) void t2tab_kernel(float* __restrict__ wsf){
  int a = blockIdx.x, e = threadIdx.x;
  const float* P8a = wsf + OFF_P8 + (size_t)a*1024;
  float zi = wsf[OFF_HH1+e]     + P8a[e];
  float zf = wsf[OFF_HH1+256+e] + P8a[256+e];
  float zg = wsf[OFF_HH1+512+e] + P8a[512+e];
  float zo = wsf[OFF_HH1+768+e] + P8a[768+e];
  float cn = sigmf(zf)*wsf[OFF_C1+e] + sigmf(zi)*tanhfast(zg);
  ((ushort*)(wsf+OFF_H2B))[a*256+e] = f2b(sigmf(zo)*tanhfast(cn));
  wsf[OFF_C2T + a*256 + e] = cn;
}

// ---- hhmat: Out[r] = bsum + W_hh @ Hrows[r]  (MFMA, eb-sliced) ----
__global__ __launch_bounds__(64) void hhmat_kernel(
    float* __restrict__ wsf, const ushort* __restrict__ Hrows,
    float* __restrict__ Out, int R)
{
  const int nt = blockIdx.x >> 4, eb = blockIdx.x & 15;
  const int lane = threadIdx.x, ln15 = lane & 15, quad = lane >> 4;
  const ushort* FWHH = (const ushort*)(wsf + OFF_FRAG) + 262144;
  int row = nt*16 + ln15;
  int rowc = row < R ? row : R-1;

  f32x4 acc[4];
  #pragma unroll
  for (int g=0; g<4; g++) acc[g] = (f32x4){0.f,0.f,0.f,0.f};
  #pragma unroll
  for (int ks=0; ks<8; ks++){
    bf16x8 b = *(const bf16x8*)&Hrows[rowc*256 + ks*32 + quad*8];
    #pragma unroll
    for (int g=0; g<4; g++){
      int mt = g*16 + eb;
      bf16x8 a = *(const bf16x8*)&FWHH[((mt*8+ks)<<9) + (lane<<3)];
      acc[g] = __builtin_amdgcn_mfma_f32_16x16x32_bf16(a, b, acc[g], 0,0,0);
    }
  }
  if (row < R){
    #pragma unroll
    for (int g=0; g<4; g++){
      int m = g*256 + eb*16 + quad*4;
      float4 bs = *(const float4*)&wsf[OFF_BSUM + m];
      *(float4*)&Out[(size_t)row*1024 + m] =
        (float4){acc[g][0]+bs.x, acc[g][1]+bs.y, acc[g][2]+bs.z, acc[g][3]+bs.w};
    }
  }
}

// ---- t3 table: (h3,c3)[a*26+b] = gate(HH2A[a] + P8[b], cp=C2[a]) ----
__global__ __launch_bounds__(256) void t3tab_kernel(float* __restrict__ wsf){
  int p = blockIdx.x;
  int a = p / 26, b = p - a*26;
  int e = threadIdx.x;
  const float* HA = wsf + OFF_HH2A + (size_t)a*1024;
  const float* PB = wsf + OFF_P8   + (size_t)b*1024;
  float zi = HA[e]     + PB[e];
  float zf = HA[256+e] + PB[256+e];
  float zg = HA[512+e] + PB[512+e];
  float zo = HA[768+e] + PB[768+e];
  float cn = sigmf(zf)*wsf[OFF_C2T + a*256 + e] + sigmf(zi)*tanhfast(zg);
  ((ushort*)(wsf+OFF_H3B))[p*256+e] = f2b(sigmf(zo)*tanhfast(cn));
  wsf[OFF_C3T + p*256 + e] = cn;
}

// ---- l7f: fully fused L7 per-node kernel (full-row blocks of 16 nodes).
// Staging: serial-16, all 256 threads on one node/iter (proven form). ----
__global__ __launch_bounds__(256) void l7f_kernel(
    const float* __restrict__ wsf, const int* __restrict__ idents,
    ushort* __restrict__ OutNext)
{
  __shared__ __align__(16) ushort HbL[16*STR];   // h4, reused for comb
  __shared__ __align__(16) ushort H5L[16*STR];
  __shared__ float C4L[16*264];
  __shared__ float wred[4][16];
  const int tid=threadIdx.x, wv=tid>>6, lane=tid&63, ln15=lane&15, quad=lane>>4;
  const ushort* FWHH = (const ushort*)(wsf + OFF_FRAG) + 262144;
  const ushort* FWC1 = FWHH + 262144;
  const ushort* FWT  = FWC1 + 65536;
  const float*  EWcP = wsf + OFF_EWC;
  const int nb = blockIdx.x*16;

  #pragma unroll 2
  for (int i=0; i<16; i++){
    const int ib4 = 21845 + (nb+i)*4;
    const int ia = idents[ib4], ibb = idents[ib4+1], icc = idents[ib4+2];
    const int pp = ia*26 + ibb;
    const float* HA = wsf + OFF_HH3 + (size_t)pp*1024;
    const float* PB = wsf + OFF_P8  + (size_t)icc*1024;
    const int e = tid;
    float zi = HA[e]     + PB[e];
    float zf = HA[256+e] + PB[256+e];
    float zg = HA[512+e] + PB[512+e];
    float zo = HA[768+e] + PB[768+e];
    float cn = sigmf(zf)*wsf[OFF_C3T + (size_t)pp*256 + e] + sigmf(zi)*tanhfast(zg);
    C4L[i*264 + e] = cn;
    HbL[i*STR + e] = f2b(sigmf(zo)*tanhfast(cn));
  }
  __syncthreads();

  const int node = nb + ln15;
  const int idd = idents[21845 + node*4 + 3];
  const float* PD = wsf + OFF_P8 + (size_t)idd*1024;

  #pragma unroll 1
  for (int p=0; p<4; p++){
    const int eb = wv*4 + p;
    f32x4 acc[4];
    #pragma unroll
    for (int g=0; g<4; g++) acc[g] = (f32x4){0.f,0.f,0.f,0.f};
    #pragma unroll
    for (int ks=0; ks<8; ks++){
      bf16x8 b = *(const bf16x8*)&HbL[ln15*STR + ks*32 + quad*8];
      #pragma unroll
      for (int g=0; g<4; g++){
        bf16x8 a = *(const bf16x8*)&FWHH[(((g*16+eb)*8+ks)<<9) + (lane<<3)];
        acc[g] = __builtin_amdgcn_mfma_f32_16x16x32_bf16(a, b, acc[g], 0,0,0);
      }
    }
    const int e0 = eb*16 + quad*4;
    float4 bs0 = *(const float4*)&wsf[OFF_BSUM +       e0];
    float4 bs1 = *(const float4*)&wsf[OFF_BSUM + 256 + e0];
    float4 bs2 = *(const float4*)&wsf[OFF_BSUM + 512 + e0];
    float4 bs3 = *(const float4*)&wsf[OFF_BSUM + 768 + e0];
    float4 d0 = *(const float4*)&PD[      e0];
    float4 d1 = *(const float4*)&PD[256 + e0];
    float4 d2 = *(const float4*)&PD[512 + e0];
    float4 d3 = *(const float4*)&PD[768 + e0];
    float4 cp4 = *(const float4*)&C4L[ln15*264 + e0];
    ushort hb[4];
    #pragma unroll
    for (int r=0; r<4; r++){
      float zi = acc[0][r] + ((const float*)&bs0)[r] + ((const float*)&d0)[r];
      float zf = acc[1][r] + ((const float*)&bs1)[r] + ((const float*)&d1)[r];
      float zg = acc[2][r] + ((const float*)&bs2)[r] + ((const float*)&d2)[r];
      float zo = acc[3][r] + ((const float*)&bs3)[r] + ((const float*)&d3)[r];
      float cn = sigmf(zf)*((const float*)&cp4)[r] + sigmf(zi)*tanhfast(zg);
      hb[r] = f2b(sigmf(zo)*tanhfast(cn));
    }
    uint2 uu;
    uu.x = (unsigned)hb[0] | ((unsigned)hb[1]<<16);
    uu.y = (unsigned)hb[2] | ((unsigned)hb[3]<<16);
    *(uint2*)&H5L[ln15*STR + e0] = uu;
  }
  __syncthreads();

  const int myid = idents[5461 + node];
  #pragma unroll 1
  for (int p=0; p<4; p++){
    const int mt = wv*4 + p;
    f32x4 ac = (f32x4){0.f,0.f,0.f,0.f};
    #pragma unroll
    for (int ks=0; ks<8; ks++){
      bf16x8 a = *(const bf16x8*)&FWC1[((mt*8+ks)<<9) + (lane<<3)];
      bf16x8 b = *(const bf16x8*)&H5L[ln15*STR + ks*32 + quad*8];
      ac = __builtin_amdgcn_mfma_f32_16x16x32_bf16(a, b, ac, 0,0,0);
    }
    float4 ew = *(const float4*)&EWcP[(size_t)myid*256 + mt*16 + quad*4];
    ushort cb[4];
    #pragma unroll
    for (int r=0; r<4; r++) cb[r] = f2b(ac[r] + ((const float*)&ew)[r]);
    uint2 uu;
    uu.x = (unsigned)cb[0] | ((unsigned)cb[1]<<16);
    uu.y = (unsigned)cb[2] | ((unsigned)cb[3]<<16);
    *(uint2*)&HbL[ln15*STR + mt*16 + quad*4] = uu;
  }
  __syncthreads();

  f32x4 tg[4];
  #pragma unroll 1
  for (int p=0; p<4; p++){
    const int mt = wv*4 + p;
    tg[p] = (f32x4){0.f,0.f,0.f,0.f};
    #pragma unroll
    for (int ks=0; ks<8; ks++){
      bf16x8 a = *(const bf16x8*)&FWT[((mt*8+ks)<<9) + (lane<<3)];
      bf16x8 b = *(const bf16x8*)&HbL[ln15*STR + ks*32 + quad*8];
      tg[p] = __builtin_amdgcn_mfma_f32_16x16x32_bf16(a, b, tg[p], 0,0,0);
    }
    float4 bt4 = *(const float4*)&wsf[OFF_BTF + mt*16 + quad*4];
    #pragma unroll
    for (int r=0; r<4; r++) tg[p][r] += ((const float*)&bt4)[r];
  }

  float mx = -3.0e38f;
  #pragma unroll
  for (int p=0; p<4; p++)
    #pragma unroll
    for (int r=0; r<4; r++) mx = fmaxf(mx, tg[p][r]);
  mx = fmaxf(mx, __shfl_xor(mx, 16, 64));
  mx = fmaxf(mx, __shfl_xor(mx, 32, 64));
  wred[wv][ln15] = mx;
  __syncthreads();
  float gmx = fmaxf(fmaxf(wred[0][ln15], wred[1][ln15]), fmaxf(wred[2][ln15], wred[3][ln15]));
  __syncthreads();
  float s = 0.f;
  #pragma unroll
  for (int p=0; p<4; p++)
    #pragma unroll
    for (int r=0; r<4; r++) s += __expf(tg[p][r] - gmx);
  s += __shfl_xor(s, 16, 64);
  s += __shfl_xor(s, 32, 64);
  wred[wv][ln15] = s;
  __syncthreads();
  float gs = (wred[0][ln15]+wred[1][ln15]) + (wred[2][ln15]+wred[3][ln15]);
  float lz = gmx + __logf(gs);

  #pragma unroll
  for (int p=0; p<4; p++){
    int m = (wv*4+p)*16 + quad*4;
    ushort ob[4];
    #pragma unroll
    for (int r=0; r<4; r++) ob[r] = f2b(tg[p][r] - lz);
    uint2 uu;
    uu.x = (unsigned)ob[0] | ((unsigned)ob[1]<<16);
    uu.y = (unsigned)ob[2] | ((unsigned)ob[3]<<16);
    *(uint2*)&OutNext[(size_t)node*256 + m] = uu;
  }
}

// ---- one LSTM t-step: eb-sliced, 64 thr (proven shape, VGPR ~52).
// SWZ=true (requires nTiles%8==0): all 16 eb-blocks of a node tile share
// bid%8 -> same XCD L2 (B rows fetched once, output lines merged). ----
template<bool FIRST, bool SWZ>
__global__ __launch_bounds__(64) void step_kernel(
    const float* __restrict__ wsf, const ushort* __restrict__ OutPrev,
    const ushort* __restrict__ Hin, ushort* __restrict__ Hout,
    float* __restrict__ Cbuf, int nNodes, int tm1)
{
  const int bid = blockIdx.x;
  int nt, eb;
  if (SWZ){
    const int xcd = bid & 7;
    const int j   = bid >> 3;
    eb = j & 15;
    nt = (j >> 4)*8 + xcd;
  } else {
    nt = bid >> 4;
    eb = bid & 15;
  }
  const int lane = threadIdx.x;
  const int ln15 = lane & 15;
  const int quad = lane >> 4;

  const ushort* FWIH = (const ushort*)(wsf + OFF_FRAG);
  const ushort* FWHH = FWIH + 262144;

  int node = nt*16 + ln15; if (node >= nNodes) node = nNodes-1;
  const int rowX = (node*4 + tm1) * 256;
  const int rowH = node * 256;

  f32x4 acc[4];
  #pragma unroll
  for (int g=0; g<4; g++) acc[g] = (f32x4){0.f,0.f,0.f,0.f};

  #pragma unroll
  for (int ks=0; ks<8; ks++){
    bf16x8 bx = *(const bf16x8*)&OutPrev[rowX + ks*32 + quad*8];
    bf16x8 bh;
    if (!FIRST) bh = *(const bf16x8*)&Hin[rowH + ks*32 + quad*8];
    #pragma unroll
    for (int g=0; g<4; g++){
      int mt = g*16 + eb;
      bf16x8 a = *(const bf16x8*)&FWIH[((mt*8+ks)<<9) + (lane<<3)];
      acc[g] = __builtin_amdgcn_mfma_f32_16x16x32_bf16(a, bx, acc[g], 0,0,0);
      if (!FIRST){
        bf16x8 a2 = *(const bf16x8*)&FWHH[((mt*8+ks)<<9) + (lane<<3)];
        acc[g] = __builtin_amdgcn_mfma_f32_16x16x32_bf16(a2, bh, acc[g], 0,0,0);
      }
    }
  }

  const float* baseP = wsf + (FIRST ? OFF_HH1 : OFF_BSUM);
  const int e0 = eb*16 + quad*4;
  float4 b0 = *(const float4*)&baseP[       e0];
  float4 b1 = *(const float4*)&baseP[ 256 + e0];
  float4 b2 = *(const float4*)&baseP[ 512 + e0];
  float4 b3 = *(const float4*)&baseP[ 768 + e0];
  float4 cp;
  if (FIRST) cp = *(const float4*)&wsf[OFF_C1 + e0];
  else       cp = *(const float4*)&Cbuf[rowH + e0];

  float cn4[4]; ushort hb[4];
  #pragma unroll
  for (int r=0; r<4; r++){
    float zi = acc[0][r] + ((const float*)&b0)[r];
    float zf = acc[1][r] + ((const float*)&b1)[r];
    float zg = acc[2][r] + ((const float*)&b2)[r];
    float zo = acc[3][r] + ((const float*)&b3)[r];
    float cn = sigmf(zf)*((const float*)&cp)[r] + sigmf(zi)*tanhfast(zg);
    cn4[r] = cn;
    hb[r] = f2b(sigmf(zo)*tanhfast(cn));
  }
  *(float4*)&Cbuf[rowH + e0] = (float4){cn4[0],cn4[1],cn4[2],cn4[3]};
  uint2 uu;
  uu.x = (unsigned)hb[0] | ((unsigned)hb[1]<<16);
  uu.y = (unsigned)hb[2] | ((unsigned)hb[3]<<16);
  *(uint2*)&Hout[rowH + e0] = uu;
}

// ---- epilogue for step levels: combine -> tag -> log-softmax -> out ----
template<bool FINAL>
__global__ __launch_bounds__(256) void fin_kernel(
    const float* __restrict__ wsf, const ushort* __restrict__ Hfin,
    const int* __restrict__ idents, int offL, int nNodes,
    ushort* __restrict__ OutNext, void* __restrict__ dout)
{
  __shared__ __align__(16) ushort Clds[16*STR];
  __shared__ float wred[4][16];
  const int tid  = threadIdx.x;
  const int wv   = tid >> 6;
  const int lane = tid & 63;
  const int ln15 = lane & 15;
  const int quad = lane >> 4;
  const int nt   = blockIdx.x;

  const ushort* FWIH = (const ushort*)(wsf + OFF_FRAG);
  const ushort* FWC1 = FWIH + 262144 + 262144;
  const ushort* FWT  = FWC1 + 65536;
  const float*  EWcP = wsf + OFF_EWC;

  int node = nt*16 + ln15; if (node >= nNodes) node = nNodes-1;
  const int myid = idents[offL + node];
  const int rowH = node * 256;

  #pragma unroll 1
  for (int p=0; p<4; p++){
    const int mt = wv*4 + p;
    f32x4 ac = (f32x4){0.f,0.f,0.f,0.f};
    #pragma unroll
    for (int ks=0; ks<8; ks++){
      bf16x8 a = *(const bf16x8*)&FWC1[((mt*8+ks)<<9) + (lane<<3)];
      bf16x8 b = *(const bf16x8*)&Hfin[rowH + ks*32 + quad*8];
      ac = __builtin_amdgcn_mfma_f32_16x16x32_bf16(a, b, ac, 0,0,0);
    }
    float4 ew = *(const float4*)&EWcP[(size_t)myid*256 + mt*16 + quad*4];
    ushort cb[4];
    #pragma unroll
    for (int r=0; r<4; r++) cb[r] = f2b(ac[r] + ((const float*)&ew)[r]);
    uint2 uu;
    uu.x = (unsigned)cb[0] | ((unsigned)cb[1]<<16);
    uu.y = (unsigned)cb[2] | ((unsigned)cb[3]<<16);
    *(uint2*)&Clds[ln15*STR + mt*16 + quad*4] = uu;
  }
  __syncthreads();

  f32x4 tg[4];
  #pragma unroll 1
  for (int p=0; p<4; p++){
    const int mt = wv*4 + p;
    tg[p] = (f32x4){0.f,0.f,0.f,0.f};
    #pragma unroll
    for (int ks=0; ks<8; ks++){
      bf16x8 a = *(const bf16x8*)&FWT[((mt*8+ks)<<9) + (lane<<3)];
      bf16x8 b = *(const bf16x8*)&Clds[ln15*STR + ks*32 + quad*8];
      tg[p] = __builtin_amdgcn_mfma_f32_16x16x32_bf16(a, b, tg[p], 0,0,0);
    }
    float4 bt4 = *(const float4*)&wsf[OFF_BTF + mt*16 + quad*4];
    #pragma unroll
    for (int r=0; r<4; r++) tg[p][r] += ((const float*)&bt4)[r];
  }

  float mx = -3.0e38f;
  #pragma unroll
  for (int p=0; p<4; p++)
    #pragma unroll
    for (int r=0; r<4; r++) mx = fmaxf(mx, tg[p][r]);
  mx = fmaxf(mx, __shfl_xor(mx, 16, 64));
  mx = fmaxf(mx, __shfl_xor(mx, 32, 64));
  wred[wv][ln15] = mx;
  __syncthreads();
  float gmx = fmaxf(fmaxf(wred[0][ln15], wred[1][ln15]), fmaxf(wred[2][ln15], wred[3][ln15]));
  __syncthreads();
  float s = 0.f;
  #pragma unroll
  for (int p=0; p<4; p++)
    #pragma unroll
    for (int r=0; r<4; r++) s += __expf(tg[p][r] - gmx);
  s += __shfl_xor(s, 16, 64);
  s += __shfl_xor(s, 32, 64);
  wred[wv][ln15] = s;
  __syncthreads();
  float gs = (wred[0][ln15]+wred[1][ln15]) + (wred[2][ln15]+wred[3][ln15]);
  float lz = gmx + __logf(gs);

  if (FINAL){
    if (ln15 == 0){
      const int f32o = ((const int*)wsf)[1] != 0;
      #pragma unroll
      for (int p=0; p<4; p++){
        #pragma unroll
        for (int r=0; r<4; r++){
          int m = (wv*4+p)*16 + quad*4 + r;
          float v = tg[p][r] - lz;
          if (f32o) ((float*)dout)[m] = v;
          else      ((ushort*)dout)[m] = f2b(v);
        }
      }
    }
    return;
  }
  int onode = nt*16 + ln15;
  if (onode < nNodes){
    #pragma unroll
    for (int p=0; p<4; p++){
      int m = (wv*4+p)*16 + quad*4;
      ushort ob[4];
      #pragma unroll
      for (int r=0; r<4; r++) ob[r] = f2b(tg[p][r] - lz);
      uint2 uu;
      uu.x = (unsigned)ob[0] | ((unsigned)ob[1]<<16);
      uu.y = (unsigned)ob[2] | ((unsigned)ob[3]<<16);
      *(uint2*)&OutNext[(size_t)onode*256 + m] = uu;
    }
  }
}

extern "C" void kernel_launch(void* const* d_in, const int* in_sizes, int n_in,
                              void* d_out, int out_size, void* d_ws, size_t ws_size,
                              hipStream_t stream)
{
  (void)in_sizes; (void)n_in; (void)out_size; (void)ws_size;
  const int* idents = (const int*)d_in[0];
  const void* emb   = d_in[1];
  const void* W_ih  = d_in[2];
  const void* W_hh  = d_in[3];
  const void* b_ih  = d_in[4];
  const void* b_hh  = d_in[5];
  const void* Wc    = d_in[6];
  const void* bc    = d_in[7];
  const void* Wt    = d_in[8];
  const void* bt    = d_in[9];
  const void* linit = d_in[10];

  float* wsf = (float*)d_ws;
  ushort* slabA = (ushort*)(wsf + OFF_SLABS);
  ushort* slabB = slabA + (size_t)16384*256;
  ushort* Hb0   = slabB + (size_t)4096*256;      // 4096 rows (L6-sized)
  ushort* Hb1   = Hb0 + (size_t)4096*256;
  float*  Cb    = (float*)(Hb1 + (size_t)4096*256);

  init_kernel  <<<1, 64, 0, stream>>>((int*)d_ws);
  detect_kernel<<<16, 256, 0, stream>>>((int*)d_ws, (const uint4*)W_ih);
  zpe_kernel   <<<158, 256, 0, stream>>>(wsf, W_ih, b_ih, b_hh, bt, linit, W_hh, Wc, Wt, emb, bc);
  hh1x_kernel  <<<5, 256, 0, stream>>>(wsf, W_hh, Wc);
  tag8_kernel  <<<2, 256, 0, stream>>>(wsf);
  p8_kernel    <<<32, 64, 0, stream>>>(wsf);

  // L7 child-prefix tables (parallel, proven)
  t2tab_kernel <<<NVOCAB, 256, 0, stream>>>(wsf);
  hhmat_kernel <<<32, 64, 0, stream>>>(wsf, (const ushort*)(wsf+OFF_H2B), wsf+OFF_HH2A, NVOCAB);
  t3tab_kernel <<<NVOCAB*NVOCAB, 256, 0, stream>>>(wsf);
  hhmat_kernel <<<((NVOCAB*NVOCAB+15)/16)*16, 64, 0, stream>>>(wsf, (const ushort*)(wsf+OFF_H3B), wsf+OFF_HH3, NVOCAB*NVOCAB);

  // L7: single fused kernel (h4 -> t5 -> combine -> tag -> softmax)
  l7f_kernel   <<<1024, 256, 0, stream>>>(wsf, idents, slabA);

  // L6 (4096) and L5 (1024): eb-sliced steps with XCD swizzle + fin
  step_kernel<true ,true><<<4096, 64, 0, stream>>>(wsf, slabA, nullptr, Hb1, Cb, 4096, 0);
  step_kernel<false,true><<<4096, 64, 0, stream>>>(wsf, slabA, Hb1, Hb0, Cb, 4096, 1);
  step_kernel<false,true><<<4096, 64, 0, stream>>>(wsf, slabA, Hb0, Hb1, Cb, 4096, 2);
  step_kernel<false,true><<<4096, 64, 0, stream>>>(wsf, slabA, Hb1, Hb0, Cb, 4096, 3);
  fin_kernel<false><<<256, 256, 0, stream>>>(wsf, Hb0, idents, 1365, 4096, slabB, nullptr);
  step_kernel<true ,true><<<1024, 64, 0, stream>>>(wsf, slabB, nullptr, Hb1, Cb, 1024, 0);
  step_kernel<false,true><<<1024, 64, 0, stream>>>(wsf, slabB, Hb1, Hb0, Cb, 1024, 1);
  step_kernel<false,true><<<1024, 64, 0, stream>>>(wsf, slabB, Hb0, Hb1, Cb, 1024, 2);
  step_kernel<false,true><<<1024, 64, 0, stream>>>(wsf, slabB, Hb1, Hb0, Cb, 1024, 3);
  fin_kernel<false><<<64, 256, 0, stream>>>(wsf, Hb0, idents, 341, 1024, slabA, nullptr);

  // L4..L0: proven step/fin path (no swizzle; nTiles not %8)
  struct Lv { int n, offL; ushort *P, *O; };
  const Lv lv[5] = {
    {256,  85, slabA, slabB},
    { 64,  21, slabB, slabA},
    { 16,   5, slabA, slabB},
    {  4,   1, slabB, slabA},
    {  1,   0, slabA, nullptr},
  };
  for (int i=0; i<5; i++){
    int nt = (lv[i].n + 15) / 16;
    dim3 gs(nt*16);
    step_kernel<true ,false><<<gs, 64, 0, stream>>>(wsf, lv[i].P, nullptr, Hb1, Cb, lv[i].n, 0);
    step_kernel<false,false><<<gs, 64, 0, stream>>>(wsf, lv[i].P, Hb1, Hb0, Cb, lv[i].n, 1);
    step_kernel<false,false><<<gs, 64, 0, stream>>>(wsf, lv[i].P, Hb0, Hb1, Cb, lv[i].n, 2);
    step_kernel<false,false><<<gs, 64, 0, stream>>>(wsf, lv[i].P, Hb1, Hb0, Cb, lv[i].n, 3);
    if (i < 4) fin_kernel<false><<<nt, 256, 0, stream>>>(wsf, Hb0, idents, lv[i].offL, lv[i].n, lv[i].O, nullptr);
    else       fin_kernel<true ><<<1,  256, 0, stream>>>(wsf, Hb0, idents, 0, 1, nullptr, d_out);
  }
}